// Round 14
// baseline (1194.312 us; speedup 1.0000x reference)
//
#include <hip/hip_runtime.h>

typedef short bf16x8 __attribute__((ext_vector_type(8)));
typedef float f32x4 __attribute__((ext_vector_type(4)));
typedef unsigned short ushort4v __attribute__((ext_vector_type(4)));
typedef unsigned int u32x4 __attribute__((ext_vector_type(4)));

__device__ __forceinline__ unsigned short f2bf(float f) {
  unsigned u = __float_as_uint(f);
  unsigned r = (u + 0x7FFFu + ((u >> 16) & 1u)) >> 16;
  return (unsigned short)r;
}
__device__ __forceinline__ float bf2f(unsigned short u) {
  return __uint_as_float(((unsigned)u) << 16);
}

// packed bf16 relu: zero any 16-bit half with the sign bit set
__device__ __forceinline__ bf16x8 relu_bf8(bf16x8 v) {
  u32x4 u;
  __builtin_memcpy(&u, &v, 16);
  #pragma unroll
  for (int i = 0; i < 4; i++) {
    unsigned s = u[i] & 0x80008000u;
    u[i] &= ~((s >> 15) * 0xFFFFu);
  }
  bf16x8 r;
  __builtin_memcpy(&r, &u, 16);
  return r;
}

// XCD-aware block swizzle: consecutive logical tiles land on the same XCD's
// L2 so halo re-reads hit cache. Valid when gridDim.x % 8 == 0.
__device__ __forceinline__ int xcd_swz(int bid, int n) {
  return (bid & 7) * (n >> 3) + (bid >> 3);
}

// ---------- zero the histogram ----------
__global__ void init_k(int* __restrict__ hist) {
  int t = threadIdx.x;
  if (t < 512) hist[t] = 0;
}

// ---------- codebook half-norms ----------
__global__ void cbh_k(const float* __restrict__ cb, float* __restrict__ cbh) {
  int k = blockIdx.x * 256 + threadIdx.x;
  if (k >= 512) return;
  const float* c = cb + k * 64;
  float s = 0.f;
  #pragma unroll
  for (int d = 0; d < 64; d++) s = fmaf(c[d], c[d], s);
  cbh[k] = 0.5f * s;
}

// ---------- repack codebook (512,64) -> [m(32)][ks(2)][lane][8] bf16 ----------
__global__ void repack_cbf_k(const float* __restrict__ cb,
                             unsigned short* __restrict__ cbf) {
  int idx = blockIdx.x * 256 + threadIdx.x;
  if (idx >= 32768) return;
  int j = idx & 7;
  int lane = (idx >> 3) & 63;
  int ks = (idx >> 9) & 1;
  int m = idx >> 10;
  int code = m * 16 + (lane & 15);
  int d = ks * 32 + (lane >> 4) * 8 + j;
  cbf[idx] = f2bf(cb[code * 64 + d]);
}

// ---------- repack conv3 weights (128,CIN,3,3) -> [ks][tap][M][lane][8] bf16
template <int CIN>
__global__ void repack_frag_k(const float* __restrict__ w,
                              unsigned short* __restrict__ wf) {
  int idx = blockIdx.x * 256 + threadIdx.x;
  int total = (CIN / 32) * 9 * 8 * 512;
  if (idx >= total) return;
  int j = idx & 7;
  int lane = (idx >> 3) & 63;
  int M = (idx >> 9) & 7;
  int tk = idx >> 12;
  int tap = tk % 9;
  int kstep = tk / 9;
  int co = M * 16 + (lane & 15);
  int ci = kstep * 32 + (lane >> 4) * 8 + j;
  wf[idx] = f2bf(w[((size_t)co * CIN + ci) * 9 + tap]);
}

// ---------- repack e1 weights (64,3,4,4) -> [ks(2)][m(4)][lane][8], K pad->64
__global__ void repack_e1f_k(const float* __restrict__ w,
                             unsigned short* __restrict__ wf) {
  int idx = blockIdx.x * 256 + threadIdx.x;
  if (idx >= 4096) return;
  int j = idx & 7;
  int lane = (idx >> 3) & 63;
  int m = (idx >> 9) & 3;
  int ks = idx >> 11;
  int co = m * 16 + (lane & 15);
  int k = ks * 32 + (lane >> 4) * 8 + j;   // k = ci*16 + ky*4 + kx
  float v = (k < 48) ? w[co * 48 + k] : 0.f;
  wf[idx] = f2bf(v);
}

// ---------- repack e2 weights (128,64,4,4) -> [ks(2)][tap(16)][M(8)][lane][8]
__global__ void repack_e2f_k(const float* __restrict__ w,
                             unsigned short* __restrict__ wf) {
  int idx = blockIdx.x * 256 + threadIdx.x;
  if (idx >= 131072) return;
  int j = idx & 7;
  int lane = (idx >> 3) & 63;
  int M = (idx >> 9) & 7;
  int tap = (idx >> 12) & 15;
  int ks = idx >> 16;
  int co = M * 16 + (lane & 15);
  int ci = ks * 32 + (lane >> 4) * 8 + j;
  wf[idx] = f2bf(w[((size_t)co * 64 + ci) * 16 + tap]);
}

// ---------- repack pvq weights (64,128) -> [ks(4)][m(4)][lane][8]
__global__ void repack_pvf_k(const float* __restrict__ w,
                             unsigned short* __restrict__ wf) {
  int idx = blockIdx.x * 256 + threadIdx.x;
  if (idx >= 8192) return;
  int j = idx & 7;
  int lane = (idx >> 3) & 63;
  int m = (idx >> 9) & 3;
  int ks = idx >> 11;
  int co = m * 16 + (lane & 15);
  int ci = ks * 32 + (lane >> 4) * 8 + j;
  wf[idx] = f2bf(w[co * 128 + ci]);
}

// ---------- repack t1 weights (128,64,4,4) -> [par(4)][ks(4)][tap(4)][m(4)][lane][8]
__global__ void repack_t1f_k(const float* __restrict__ w,
                             unsigned short* __restrict__ wf) {
  int idx = blockIdx.x * 256 + threadIdx.x;
  if (idx >= 131072) return;
  int j = idx & 7;
  int lane = (idx >> 3) & 63;
  int m = (idx >> 9) & 3;
  int tap = (idx >> 11) & 3;
  int ks = (idx >> 13) & 3;
  int par = (idx >> 15) & 3;
  int sy = par >> 1, sx = par & 1;
  int ty = tap >> 1, tx = tap & 1;
  int ky = sy ? (ty ? 0 : 2) : (ty ? 1 : 3);
  int kx = sx ? (tx ? 0 : 2) : (tx ? 1 : 3);
  int co = m * 16 + (lane & 15);
  int ci = ks * 32 + (lane >> 4) * 8 + j;
  wf[idx] = f2bf(w[((size_t)ci * 64 + co) * 16 + ky * 4 + kx]);
}

// ---------- repack t2 weights (64,3,4,4) -> [par(4)][ks(2)][tap(4)][lane][8]
__global__ void repack_t2f_k(const float* __restrict__ w,
                             unsigned short* __restrict__ wf) {
  int idx = blockIdx.x * 256 + threadIdx.x;
  if (idx >= 16384) return;
  int j = idx & 7;
  int lane = (idx >> 3) & 63;
  int tap = (idx >> 9) & 3;
  int ks = (idx >> 11) & 1;
  int par = idx >> 12;
  int sy = par >> 1, sx = par & 1;
  int ty = tap >> 1, tx = tap & 1;
  int ky = sy ? (ty ? 0 : 2) : (ty ? 1 : 3);
  int kx = sx ? (tx ? 0 : 2) : (tx ? 1 : 3);
  int co = lane & 15;
  int ci = ks * 32 + (lane >> 4) * 8 + j;
  float v = (co < 3) ? w[((size_t)ci * 3 + co) * 16 + ky * 4 + kx] : 0.f;
  wf[idx] = f2bf(v);
}

// ---------- e1 via MFMA: conv 4x4 s2 p1, 3->64, bias+ReLU -> bf16 NHWC ------
__global__ __launch_bounds__(256, 4) void e1m_k(
    const float* __restrict__ x, const unsigned short* __restrict__ wf,
    const float* __restrict__ bias, unsigned short* __restrict__ out) {
  __shared__ unsigned short patch[128 * 72];
  int blk = xcd_swz(blockIdx.x, gridDim.x);
  int b = blk >> 7;
  int oy = blk & 127;
  int t = threadIdx.x;
  int w = t >> 6, l = t & 63;
  int cib = (l >> 4) * 8, colb = l & 15;
  const float* xb = x + (size_t)b * 3 * 65536;
  {
    int p = t & 127;
    int kb = (t >> 7) * 32;          // this thread stages k [kb, kb+32)
    int px2 = 2 * p - 1;
    int oy2 = 2 * oy - 1;
    bf16x8 pk[4];
    #pragma unroll
    for (int c = 0; c < 4; c++) {
      #pragma unroll
      for (int j = 0; j < 8; j++) {
        int k = kb + c * 8 + j;      // k = ci*16 + ky*4 + kx (>=48 -> pad 0)
        float v = 0.f;
        if (k < 48) {
          int ci = k >> 4;
          int ky = (k >> 2) & 3, kx = k & 3;
          int iy = oy2 + ky, ix = px2 + kx;
          if ((unsigned)iy < 256u && (unsigned)ix < 256u)
            v = xb[ci * 65536 + iy * 256 + ix];
        }
        pk[c][j] = (short)f2bf(v);
      }
    }
    unsigned short* row = &patch[p * 72 + kb];
    #pragma unroll
    for (int c = 0; c < 4; c++)
      *(bf16x8*)&row[c * 8] = pk[c];
  }
  __syncthreads();
  f32x4 acc[8];
  #pragma unroll
  for (int n = 0; n < 8; n++) acc[n] = (f32x4){0.f, 0.f, 0.f, 0.f};
  #pragma unroll
  for (int ks = 0; ks < 2; ks++) {
    bf16x8 af = *(const bf16x8*)&wf[((size_t)(ks * 4 + w) * 64 + l) * 8];
    #pragma unroll
    for (int n = 0; n < 8; n++) {
      bf16x8 bfrag =
          *(const bf16x8*)&patch[(n * 16 + colb) * 72 + ks * 32 + cib];
      acc[n] = __builtin_amdgcn_mfma_f32_16x16x32_bf16(af, bfrag, acc[n],
                                                       0, 0, 0);
    }
  }
  int cob = w * 16 + (l >> 4) * 4;
  f32x4 bj = *(const f32x4*)&bias[cob];
  #pragma unroll
  for (int n = 0; n < 8; n++) {
    int p = n * 16 + colb;
    ushort4v pk = {f2bf(fmaxf(acc[n][0] + bj[0], 0.f)),
                   f2bf(fmaxf(acc[n][1] + bj[1], 0.f)),
                   f2bf(fmaxf(acc[n][2] + bj[2], 0.f)),
                   f2bf(fmaxf(acc[n][3] + bj[3], 0.f))};
    *(ushort4v*)&out[((size_t)b * 16384 + oy * 128 + p) * 64 + cob] = pk;
  }
}

// ---------- e2 via MFMA, async-staged (global_load_lds): 4x4 s2 p1, 64->128 -
// Proven R11: LDS linear [2112 chunks][16B]; bank swizzle on GLOBAL source
// (chunk q ^ ((pos>>1)&3)); reads apply same XOR; halo lanes ds_write zeros.
__global__ __launch_bounds__(256, 4) void e2m_k(
    const unsigned short* __restrict__ in,  // bf16 NHWC (b,128,128,64)
    const unsigned short* __restrict__ wf, const float* __restrict__ bias,
    unsigned short* __restrict__ out) {     // bf16 NHWC (b,64,64,128) pre-act
  __shared__ unsigned short patch[528 * 32];
  int blk = xcd_swz(blockIdx.x, gridDim.x);
  int b = blk >> 6;
  int oy = blk & 63;
  int t = threadIdx.x;
  int w = t >> 6, l = t & 63;      // w = M-quarter: co [32w, 32w+32)
  int qr = l >> 4, colb = l & 15;
  f32x4 acc[2][4];
  #pragma unroll
  for (int m = 0; m < 2; m++)
    #pragma unroll
    for (int n = 0; n < 4; n++) acc[m][n] = (f32x4){0.f, 0.f, 0.f, 0.f};
  const unsigned short* inb = in + (size_t)b * 16384 * 64;
  for (int ks = 0; ks < 2; ks++) {
    __syncthreads();
    // async-stage 2112 chunks (4 rows x 132 cols x 4x8ci), even/odd col split
    for (int j = 0; j < 9; j++) {
      int base_chunk = j * 256 + w * 64;   // wave-uniform
      if (base_chunk >= 2112) break;
      int chunk = base_chunk + l;
      int pos = chunk >> 2, qs = chunk & 3;
      int r = pos / 132, s2 = pos - r * 132;
      int cr = (s2 < 66) ? (2 * s2) : (2 * (s2 - 66) + 1);
      int iy = 2 * oy - 1 + r, ix = cr - 1;
      int qg = qs ^ ((pos >> 1) & 3);
      if ((unsigned)iy < 128u && (unsigned)ix < 128u) {
        __builtin_amdgcn_global_load_lds(
            (const __attribute__((address_space(1))) unsigned int*)(const void*)
                &inb[((size_t)iy * 128 + ix) * 64 + ks * 32 + qg * 8],
            (__attribute__((address_space(3))) unsigned int*)(void*)
                &patch[(size_t)base_chunk * 8],
            16, 0, 0);
      } else {
        *(bf16x8*)&patch[chunk * 8] = (bf16x8){0, 0, 0, 0, 0, 0, 0, 0};
      }
    }
    __syncthreads();
    __builtin_amdgcn_s_setprio(1);
    #pragma unroll
    for (int tap = 0; tap < 16; tap++) {
      int ky = tap >> 2, kx = tap & 3;
      bf16x8 bfrag[4];
      #pragma unroll
      for (int n = 0; n < 4; n++) {
        int ox = n * 16 + colb;
        int pos = ky * 132 + (kx & 1) * 66 + ox + (kx >> 1);
        int qsl = qr ^ ((pos >> 1) & 3);
        bfrag[n] = *(const bf16x8*)&patch[pos * 32 + qsl * 8];
      }
      const unsigned short* wft = wf + ((size_t)(ks * 16 + tap) * 8) * 512;
      #pragma unroll
      for (int m = 0; m < 2; m++) {
        bf16x8 af = *(const bf16x8*)&wft[((w * 2 + m) * 64 + l) * 8];
        #pragma unroll
        for (int n = 0; n < 4; n++)
          acc[m][n] = __builtin_amdgcn_mfma_f32_16x16x32_bf16(af, bfrag[n],
                                                              acc[m][n], 0, 0, 0);
      }
    }
    __builtin_amdgcn_s_setprio(0);
  }
  #pragma unroll
  for (int m = 0; m < 2; m++) {
    int cob = (w * 2 + m) * 16 + qr * 4;
    f32x4 bj = *(const f32x4*)&bias[cob];
    #pragma unroll
    for (int n = 0; n < 4; n++) {
      int ox = n * 16 + colb;
      size_t adr = ((size_t)(b * 4096 + oy * 64 + ox)) * 128 + cob;
      ushort4v pre = {f2bf(acc[m][n][0] + bj[0]), f2bf(acc[m][n][1] + bj[1]),
                      f2bf(acc[m][n][2] + bj[2]), f2bf(acc[m][n][3] + bj[3])};
      *(ushort4v*)&out[adr] = pre;
    }
  }
}

// ---------- conv3 via MFMA, LDS-staged NHWC: 3x3 s1 p1, CIN->128 on 64x64 ---
// R11-proven form (reg-staged, BK=64 two planes, stride 36). Rule: this
// family changes only with byte-level address-pattern preservation
// (R3/R7/R12 all regressed it structurally).
template <int CIN, bool RES_ADD, bool RELU_IN, bool HAS_BIAS, bool PRE_ONLY>
__global__ __launch_bounds__(256, 4) void conv3nh_k(
    const unsigned short* __restrict__ in,   // bf16 NHWC (b,64,64,CIN)
    const unsigned short* __restrict__ wf,
    const float* __restrict__ bias,
    const unsigned short* __restrict__ res,  // bf16 NHWC (b,64,64,128) or null
    unsigned short* __restrict__ out) {      // bf16 NHWC (b,64,64,128)
  constexpr int KO = CIN / 64;               // outer K-steps (BK=64)
  __shared__ unsigned short patch[2 * 264 * 36];
  int blk = xcd_swz(blockIdx.x, gridDim.x);
  int b = blk >> 5;
  int tile = blk & 31;
  int y0 = tile * 2;
  int t = threadIdx.x;
  int w = t >> 6, l = t & 63;
  int wm = w >> 1, wn = w & 1;
  int n0 = wn * 64;
  int cib = (l >> 4) * 8, colb = l & 15;
  f32x4 acc[4][4];
  #pragma unroll
  for (int m = 0; m < 4; m++)
    #pragma unroll
    for (int n = 0; n < 4; n++) acc[m][n] = (f32x4){0.f, 0.f, 0.f, 0.f};
  const unsigned short* inb = in + (size_t)b * 4096 * CIN;
  for (int ko = 0; ko < KO; ko++) {
    __syncthreads();
    // stage 4 rows x 66 cols x 64 ci as 16B chunks into 2 planes (ksi 0/1)
    for (int idx = t; idx < 2112; idx += 256) {
      int q = idx & 7;             // 8 chunks of 8 ci = 64 ci
      int pos = idx >> 3;          // < 264
      int r = pos / 66, c = pos - r * 66;
      int y = y0 - 1 + r, x = c - 1;
      bf16x8 v = (bf16x8){0, 0, 0, 0, 0, 0, 0, 0};
      if ((unsigned)y < 64u && (unsigned)x < 64u)
        v = *(const bf16x8*)&inb[((size_t)(y * 64 + x)) * CIN + ko * 64 + q * 8];
      if (RELU_IN) v = relu_bf8(v);
      int ksi = q >> 2, qq = q & 3;
      *(bf16x8*)&patch[ksi * 9504 + pos * 36 + qq * 8] = v;
    }
    __syncthreads();
    __builtin_amdgcn_s_setprio(1);
    #pragma unroll
    for (int tap = 0; tap < 9; tap++) {
      int ky = tap / 3, kx = tap % 3;
      #pragma unroll
      for (int ksi = 0; ksi < 2; ksi++) {
        bf16x8 bfrag[4];
        #pragma unroll
        for (int n = 0; n < 4; n++) {
          int p = n0 + n * 16 + colb;
          int pr = p >> 6, pc = p & 63;
          int pos = (pr + ky) * 66 + (pc + kx);
          bfrag[n] = *(const bf16x8*)&patch[ksi * 9504 + pos * 36 + cib];
        }
        const unsigned short* wft =
            wf + (size_t)(ko * 2 + ksi) * 9 * 4096 + (size_t)tap * 4096;
        bf16x8 afrag[4];
        #pragma unroll
        for (int m = 0; m < 4; m++)
          afrag[m] = *(const bf16x8*)&wft[((wm * 4 + m) * 64 + l) * 8];
        #pragma unroll
        for (int m = 0; m < 4; m++)
          #pragma unroll
          for (int n = 0; n < 4; n++)
            acc[m][n] = __builtin_amdgcn_mfma_f32_16x16x32_bf16(
                afrag[m], bfrag[n], acc[m][n], 0, 0, 0);
      }
    }
    __builtin_amdgcn_s_setprio(0);
  }
  #pragma unroll
  for (int m = 0; m < 4; m++) {
    int cobase = wm * 64 + m * 16 + (l >> 4) * 4;
    float b0 = HAS_BIAS ? bias[cobase] : 0.f;
    float b1 = HAS_BIAS ? bias[cobase + 1] : 0.f;
    float b2 = HAS_BIAS ? bias[cobase + 2] : 0.f;
    float b3 = HAS_BIAS ? bias[cobase + 3] : 0.f;
    #pragma unroll
    for (int n = 0; n < 4; n++) {
      int p = n0 + n * 16 + colb;
      size_t adr = ((size_t)(b * 4096 + tile * 128 + p)) * 128 + cobase;
      float f0 = acc[m][n][0] + b0, f1 = acc[m][n][1] + b1;
      float f2 = acc[m][n][2] + b2, f3 = acc[m][n][3] + b3;
      if (RES_ADD) {
        ushort4v rv = *(const ushort4v*)&res[adr];
        f0 += bf2f(rv.x); f1 += bf2f(rv.y); f2 += bf2f(rv.z); f3 += bf2f(rv.w);
      }
      ushort4v pk;
      if (PRE_ONLY) {
        pk.x = f2bf(f0); pk.y = f2bf(f1); pk.z = f2bf(f2); pk.w = f2bf(f3);
      } else {
        pk.x = f2bf(fmaxf(f0, 0.f)); pk.y = f2bf(fmaxf(f1, 0.f));
        pk.z = f2bf(fmaxf(f2, 0.f)); pk.w = f2bf(fmaxf(f3, 0.f));
      }
      *(ushort4v*)&out[adr] = pk;
    }
  }
}

// ---------- fused VQ: pvq 1x1 conv -> z in LDS -> argmin -> apply + loss ----
__global__ __launch_bounds__(256, 2) void vqf_k(
    const unsigned short* __restrict__ in,  // bf16 NHWC (b,64,64,128)
    const unsigned short* __restrict__ wf, const float* __restrict__ bias,
    const unsigned short* __restrict__ cbf, const float* __restrict__ cbh,
    const float* __restrict__ cb,
    unsigned short* __restrict__ q,         // Qbf out (bf16 NHWC)
    unsigned short* __restrict__ bidx,
    float* __restrict__ part, int part_off) {
  __shared__ unsigned short zt[256 * 72];
  __shared__ unsigned short bidx_s[256];
  __shared__ float red[256];
  int blk = blockIdx.x;
  int b = blk >> 4;
  int hw0 = (blk & 15) * 256;
  int t = threadIdx.x;
  int w = t >> 6, l = t & 63;
  int n0 = w * 64;
  int cib = (l >> 4) * 8, colb = l & 15;
  // ---- phase 1: pvq 1x1 conv 128->64 + bias, z -> LDS only ----
  {
    f32x4 acc[4][4];
    #pragma unroll
    for (int m = 0; m < 4; m++)
      #pragma unroll
      for (int n = 0; n < 4; n++) acc[m][n] = (f32x4){0.f, 0.f, 0.f, 0.f};
    const unsigned short* inb = in + ((size_t)(b * 4096 + hw0)) * 128;
    for (int ks = 0; ks < 4; ks++) {
      bf16x8 bfrag[4];
      #pragma unroll
      for (int n = 0; n < 4; n++) {
        int p = n0 + n * 16 + colb;
        bfrag[n] = *(const bf16x8*)&inb[(size_t)p * 128 + ks * 32 + cib];
      }
      const unsigned short* wk = wf + ks * 4 * 512;
      #pragma unroll
      for (int m = 0; m < 4; m++) {
        bf16x8 af = *(const bf16x8*)&wk[(m * 64 + l) * 8];
        #pragma unroll
        for (int n = 0; n < 4; n++)
          acc[m][n] = __builtin_amdgcn_mfma_f32_16x16x32_bf16(af, bfrag[n],
                                                              acc[m][n], 0, 0, 0);
      }
    }
    #pragma unroll
    for (int m = 0; m < 4; m++) {
      int d0 = m * 16 + (l >> 4) * 4;
      f32x4 bj = *(const f32x4*)&bias[d0];
      #pragma unroll
      for (int n = 0; n < 4; n++) {
        int p = n0 + n * 16 + colb;
        ushort4v pk = {f2bf(acc[m][n][0] + bj[0]), f2bf(acc[m][n][1] + bj[1]),
                       f2bf(acc[m][n][2] + bj[2]), f2bf(acc[m][n][3] + bj[3])};
        *(ushort4v*)&zt[p * 72 + d0] = pk;
      }
    }
  }
  __syncthreads();
  // ---- phase 2: argmin over 512 codes via MFMA (z from LDS) ----
  {
    bf16x8 zfrag[4][2];
    #pragma unroll
    for (int n = 0; n < 4; n++) {
      int p = n0 + n * 16 + colb;
      #pragma unroll
      for (int k2 = 0; k2 < 2; k2++)
        zfrag[n][k2] = *(const bf16x8*)&zt[p * 72 + k2 * 32 + cib];
    }
    float best[4];
    int bid[4];
    #pragma unroll
    for (int n = 0; n < 4; n++) { best[n] = -1e30f; bid[n] = 0; }
    for (int m = 0; m < 32; m++) {
      bf16x8 a0 = *(const bf16x8*)&cbf[((size_t)(m * 2 + 0) * 64 + l) * 8];
      bf16x8 a1 = *(const bf16x8*)&cbf[((size_t)(m * 2 + 1) * 64 + l) * 8];
      int code0 = m * 16 + (l >> 4) * 4;
      f32x4 ch = *(const f32x4*)&cbh[code0];
      #pragma unroll
      for (int n = 0; n < 4; n++) {
        f32x4 acc2 = (f32x4){0.f, 0.f, 0.f, 0.f};
        acc2 = __builtin_amdgcn_mfma_f32_16x16x32_bf16(a0, zfrag[n][0], acc2, 0, 0, 0);
        acc2 = __builtin_amdgcn_mfma_f32_16x16x32_bf16(a1, zfrag[n][1], acc2, 0, 0, 0);
        #pragma unroll
        for (int r = 0; r < 4; r++) {
          float sc = acc2[r] - ch[r];
          if (sc > best[n]) { best[n] = sc; bid[n] = code0 + r; }
        }
      }
    }
    #pragma unroll
    for (int n = 0; n < 4; n++) {
      #pragma unroll
      for (int off = 16; off <= 32; off <<= 1) {
        float ob = __shfl_xor(best[n], off, 64);
        int oi = __shfl_xor(bid[n], off, 64);
        if (ob > best[n] || (ob == best[n] && oi < bid[n])) {
          best[n] = ob;
          bid[n] = oi;
        }
      }
      if ((l >> 4) == 0) bidx_s[n0 + n * 16 + colb] = (unsigned short)bid[n];
    }
  }
  __syncthreads();
  int bi = bidx_s[t];
  bidx[(size_t)b * 4096 + hw0 + t] = (unsigned short)bi;
  // ---- phase 3: apply (q = cb[idx]) + loss partial (z from LDS) ----
  {
    const float* cq = cb + bi * 64;
    unsigned short* qp = q + ((size_t)(b * 4096 + hw0 + t)) * 64;
    const unsigned short* zp = &zt[t * 72];
    float ls = 0.f;
    #pragma unroll
    for (int g = 0; g < 8; g++) {
      u32x4 zv = *(const u32x4*)&zp[g * 8];
      u32x4 qv;
      #pragma unroll
      for (int h = 0; h < 4; h++) {
        int d = g * 8 + h * 2;
        float q0 = cq[d], q1 = cq[d + 1];
        float z0 = __uint_as_float(zv[h] << 16);
        float z1 = __uint_as_float(zv[h] & 0xFFFF0000u);
        float d0 = q0 - z0, d1 = q1 - z1;
        ls = fmaf(d0, d0, ls);
        ls = fmaf(d1, d1, ls);
        qv[h] = (unsigned)f2bf(q0) | ((unsigned)f2bf(q1) << 16);
      }
      *(u32x4*)&qp[g * 8] = qv;
    }
    red[t] = ls;
    __syncthreads();
    for (int s = 128; s > 0; s >>= 1) {
      if (t < s) red[t] += red[t + s];
      __syncthreads();
    }
    if (t == 0) part[part_off + blk] = red[0];
  }
}

// ---------- histogram from index array ----------
__global__ __launch_bounds__(1024) void vq_hist_k(
    const unsigned short* __restrict__ bidx, int* __restrict__ hist) {
  __shared__ int hl[512];
  int t = threadIdx.x;
  if (t < 512) hl[t] = 0;
  __syncthreads();
  int base = blockIdx.x * 16384;
  for (int i = t; i < 16384; i += 1024)
    atomicAdd(&hl[bidx[base + i]], 1);
  __syncthreads();
  if (t < 512 && hl[t] > 0) atomicAdd(&hist[t], hl[t]);
}

// ---------- t1 via MFMA, async-staged NHWC: convT 4x4 s2 p1, 128->64 --------
// R14: launch_bounds (256,2)->(256,4). R13 counters: occupancy 18% == the
// 2-block request itself; VGPR 124 and LDS 17.4KB both admit 4 blocks/CU.
// Doubling residency lets block A's staging overlap block B's compute.
__global__ __launch_bounds__(256, 4) void t1m_k(
    const unsigned short* __restrict__ in,  // bf16 NHWC (b,64,64,128)
    const unsigned short* __restrict__ wf, const float* __restrict__ bias,
    unsigned short* __restrict__ out) {     // bf16 NHWC (b,128,128,64)
  __shared__ unsigned short patch[1088 * 8];
  int blk = xcd_swz(blockIdx.x, gridDim.x);
  int b = blk >> 5;
  int a0 = (blk & 31) * 2;
  int t = threadIdx.x;
  int w = t >> 6, l = t & 63;
  int sy = w >> 1, sx = w & 1;
  int qr = l >> 4, colb = l & 15;
  f32x4 acc[4][8];
  #pragma unroll
  for (int m = 0; m < 4; m++)
    #pragma unroll
    for (int n = 0; n < 8; n++) acc[m][n] = (f32x4){0.f, 0.f, 0.f, 0.f};
  const unsigned short* inb = in + (size_t)b * 4096 * 128;
  for (int ks = 0; ks < 4; ks++) {
    __syncthreads();
    for (int j = 0; j < 5; j++) {
      int base_chunk = j * 256 + w * 64;   // wave-uniform
      if (base_chunk >= 1088) break;
      int chunk = base_chunk + l;
      int pos = chunk >> 2, qs = chunk & 3;
      int r = pos / 66, c = pos - r * 66;
      int y = a0 - 1 + r, x = c - 1;
      int qg = qs ^ ((pos >> 1) & 3);
      if (pos < 264 && (unsigned)y < 64u && (unsigned)x < 64u) {
        __builtin_amdgcn_global_load_lds(
            (const __attribute__((address_space(1))) unsigned int*)(const void*)
                &inb[((size_t)(y * 64 + x)) * 128 + ks * 32 + qg * 8],
            (__attribute__((address_space(3))) unsigned int*)(void*)
                &patch[(size_t)base_chunk * 8],
            16, 0, 0);
      } else {
        *(bf16x8*)&patch[chunk * 8] = (bf16x8){0, 0, 0, 0, 0, 0, 0, 0};
      }
    }
    __syncthreads();
    __builtin_amdgcn_s_setprio(1);
    const unsigned short* wpar = wf + (size_t)((sy * 2 + sx) * 4 + ks) * 8192;
    #pragma unroll
    for (int tap = 0; tap < 4; tap++) {
      int ty = tap >> 1, tx = tap & 1;
      int d = sy ? ty + 1 : ty;
      int e = sx ? tx + 1 : tx;
      bf16x8 bfrag[8];
      #pragma unroll
      for (int n = 0; n < 8; n++) {
        int p = n * 16 + colb;
        int ar = p >> 6, pc = p & 63;
        int pos = (ar + d) * 66 + (pc + e);
        int qsl = qr ^ ((pos >> 1) & 3);
        bfrag[n] = *(const bf16x8*)&patch[pos * 32 + qsl * 8];
      }
      bf16x8 afrag[4];
      #pragma unroll
      for (int m = 0; m < 4; m++)
        afrag[m] = *(const bf16x8*)&wpar[(tap * 256 + m * 64 + l) * 8];
      #pragma unroll
      for (int m = 0; m < 4; m++)
        #pragma unroll
        for (int n = 0; n < 8; n++)
          acc[m][n] = __builtin_amdgcn_mfma_f32_16x16x32_bf16(
              afrag[m], bfrag[n], acc[m][n], 0, 0, 0);
    }
    __builtin_amdgcn_s_setprio(0);
  }
  #pragma unroll
  for (int m = 0; m < 4; m++) {
    int cob = m * 16 + (l >> 4) * 4;
    float b0 = bias[cob], b1 = bias[cob + 1], b2 = bias[cob + 2],
          b3 = bias[cob + 3];
    #pragma unroll
    for (int n = 0; n < 8; n++) {
      int p = n * 16 + colb;
      int ar = p >> 6, pc = p & 63;
      int oy = 2 * (a0 + ar) + sy, ox = 2 * pc + sx;
      ushort4v pk;
      pk.x = f2bf(fmaxf(acc[m][n][0] + b0, 0.f));
      pk.y = f2bf(fmaxf(acc[m][n][1] + b1, 0.f));
      pk.z = f2bf(fmaxf(acc[m][n][2] + b2, 0.f));
      pk.w = f2bf(fmaxf(acc[m][n][3] + b3, 0.f));
      *(ushort4v*)&out[((size_t)b * 16384 + oy * 128 + ox) * 64 + cob] = pk;
    }
  }
}

// ---------- t2 via MFMA, async-staged NHWC: convT 4x4 s2 p1, 64->3 ----------
// R14: launch_bounds (256,2)->(256,4); LDS 33.8KB admits 4 blocks/CU.
__global__ __launch_bounds__(256, 4) void t2m_k(
    const unsigned short* __restrict__ in,  // bf16 NHWC (b,128,128,64)
    const unsigned short* __restrict__ wf,
    const float* __restrict__ bias, float* __restrict__ out) {
  __shared__ unsigned short patch[2112 * 8];
  int blk = xcd_swz(blockIdx.x, gridDim.x);
  int b = blk >> 6;
  int a0 = (blk & 63) * 2;
  int t = threadIdx.x;
  int w = t >> 6, l = t & 63;
  int sy = w >> 1, sx = w & 1;
  int qr = l >> 4, colb = l & 15;
  f32x4 acc[2][8];
  #pragma unroll
  for (int ar = 0; ar < 2; ar++)
    #pragma unroll
    for (int n = 0; n < 8; n++) acc[ar][n] = (f32x4){0.f, 0.f, 0.f, 0.f};
  bf16x8 af[2][4];
  #pragma unroll
  for (int ks = 0; ks < 2; ks++) {
    const unsigned short* wpar = wf + (size_t)((sy * 2 + sx) * 2 + ks) * 2048;
    #pragma unroll
    for (int tap = 0; tap < 4; tap++)
      af[ks][tap] = *(const bf16x8*)&wpar[(tap * 64 + l) * 8];
  }
  const unsigned short* inb = in + (size_t)b * 16384 * 64;
  for (int ks = 0; ks < 2; ks++) {
    __syncthreads();
    for (int j = 0; j < 9; j++) {
      int base_chunk = j * 256 + w * 64;   // wave-uniform
      if (base_chunk >= 2112) break;
      int chunk = base_chunk + l;
      int pos = chunk >> 2, qs = chunk & 3;
      int r = pos / 132, c = pos - r * 132;
      int y = a0 - 1 + r, x = c - 1;
      int qg = qs ^ ((pos >> 1) & 3);
      if ((unsigned)y < 128u && (unsigned)x < 128u) {
        __builtin_amdgcn_global_load_lds(
            (const __attribute__((address_space(1))) unsigned int*)(const void*)
                &inb[((size_t)(y * 128 + x)) * 64 + ks * 32 + qg * 8],
            (__attribute__((address_space(3))) unsigned int*)(void*)
                &patch[(size_t)base_chunk * 8],
            16, 0, 0);
      } else {
        *(bf16x8*)&patch[chunk * 8] = (bf16x8){0, 0, 0, 0, 0, 0, 0, 0};
      }
    }
    __syncthreads();
    __builtin_amdgcn_s_setprio(1);
    #pragma unroll
    for (int tap = 0; tap < 4; tap++) {
      int ty = tap >> 1, tx = tap & 1;
      int d = sy ? ty + 1 : ty;
      int e = sx ? tx + 1 : tx;
      #pragma unroll
      for (int ar = 0; ar < 2; ar++) {
        #pragma unroll
        for (int n = 0; n < 8; n++) {
          int pc = n * 16 + colb;
          int pos = (ar + d) * 132 + (pc + e);
          int qsl = qr ^ ((pos >> 1) & 3);
          bf16x8 bfrag = *(const bf16x8*)&patch[pos * 32 + qsl * 8];
          acc[ar][n] = __builtin_amdgcn_mfma_f32_16x16x32_bf16(
              af[ks][tap], bfrag, acc[ar][n], 0, 0, 0);
        }
      }
    }
    __builtin_amdgcn_s_setprio(0);
  }
  int rb = (l >> 4) * 4;
  #pragma unroll
  for (int r = 0; r < 4; r++) {
    int co = rb + r;
    if (co < 3) {
      float bj = bias[co];
      #pragma unroll
      for (int ar = 0; ar < 2; ar++) {
        int oy = 2 * (a0 + ar) + sy;
        #pragma unroll
        for (int n = 0; n < 8; n++) {
          int pc = n * 16 + colb;
          int ox = 2 * pc + sx;
          out[((size_t)(b * 3 + co)) * 65536 + oy * 256 + ox] = acc[ar][n][r] + bj;
        }
      }
    }
  }
}

// ---------- finalize: loss + perplexity ----------
__global__ __launch_bounds__(512) void fin_k(
    const float* __restrict__ part, const int* __restrict__ hist,
    float* __restrict__ loss_out, float* __restrict__ perp_out) {
  __shared__ float red[512];
  int t = threadIdx.x;
  red[t] = part[t];
  __syncthreads();
  for (int s = 256; s > 0; s >>= 1) {
    if (t < s) red[t] += red[t + s];
    __syncthreads();
  }
  float loss = 1.25f * red[0] / 8388608.f;
  __syncthreads();
  float p = (float)hist[t] / 131072.f;
  red[t] = -p * logf(p + 1e-10f);
  __syncthreads();
  for (int s = 256; s > 0; s >>= 1) {
    if (t < s) red[t] += red[t + s];
    __syncthreads();
  }
  if (t == 0) {
    *loss_out = loss;
    *perp_out = expf(red[0]);
  }
}

// ---------------------------------------------------------------------------
extern "C" void kernel_launch(void* const* d_in, const int* in_sizes, int n_in,
                              void* d_out, int out_size, void* d_ws, size_t ws_size,
                              hipStream_t stream) {
  (void)in_sizes; (void)n_in; (void)out_size;
  const float* x    = (const float*)d_in[0];
  const float* e1w  = (const float*)d_in[1];
  const float* e1b  = (const float*)d_in[2];
  const float* e2w  = (const float*)d_in[3];
  const float* e2b  = (const float*)d_in[4];
  const float* er11 = (const float*)d_in[5];
  const float* er12 = (const float*)d_in[6];
  const float* er21 = (const float*)d_in[7];
  const float* er22 = (const float*)d_in[8];
  const float* pvw  = (const float*)d_in[9];
  const float* pvb  = (const float*)d_in[10];
  const float* cb   = (const float*)d_in[11];
  const float* d1w  = (const float*)d_in[12];
  const float* d1b  = (const float*)d_in[13];
  const float* dr11 = (const float*)d_in[14];
  const float* dr12 = (const float*)d_in[15];
  const float* dr21 = (const float*)d_in[16];
  const float* dr22 = (const float*)d_in[17];
  const float* t1w  = (const float*)d_in[18];
  const float* t1b  = (const float*)d_in[19];
  const float* t2w  = (const float*)d_in[20];
  const float* t2b  = (const float*)d_in[21];
  float* out = (float*)d_out;

  // ---- workspace layout (float offsets) ----
  const size_t W_PVF  = 0;
  const size_t W_E2F  = W_PVF + 4096;
  const size_t W_T1F  = W_E2F + 65536;
  const size_t W_T2F  = W_T1F + 65536;
  const size_t W_D1F  = W_T2F + 8192;
  const size_t W_CBF  = W_D1F + 36864;
  const size_t W_E1F  = W_CBF + 16384;
  const size_t W_RT   = W_E1F + 2048;
  const size_t W_CBH  = W_RT + 8 * 73728;
  const size_t W_PART = W_CBH + 512;
  const size_t W_BIDX = W_PART + 512;
  const size_t W_HIST = W_BIDX + 65536;
  const size_t W_TOT  = W_HIST + 512;

  float* ws = (float*)d_ws;
  unsigned short* pvf = (unsigned short*)(ws + W_PVF);
  unsigned short* e2f = (unsigned short*)(ws + W_E2F);
  unsigned short* t1f = (unsigned short*)(ws + W_T1F);
  unsigned short* t2f = (unsigned short*)(ws + W_T2F);
  unsigned short* d1f = (unsigned short*)(ws + W_D1F);
  unsigned short* cbf = (unsigned short*)(ws + W_CBF);
  unsigned short* e1f = (unsigned short*)(ws + W_E1F);
  unsigned short* rtf[8];
  for (int i = 0; i < 8; i++)
    rtf[i] = (unsigned short*)(ws + W_RT + (size_t)i * 73728);
  float* cbh  = ws + W_CBH;
  float* part = ws + W_PART;
  unsigned short* bidx = (unsigned short*)(ws + W_BIDX);
  int*   hist = (int*)(ws + W_HIST);

  size_t wfloats = ws_size / sizeof(float);
  int BC = 32;
  while (BC > 1 && W_TOT + (size_t)BC * 1572864 > wfloats) BC >>= 1;
  int nchunk = 32 / BC;

  // dynamic buffers (bf16 NHWC): E1/T1 (overlaid), P1, P2, P4, Zbf, Qbf
  unsigned short* E1  = (unsigned short*)(ws + W_TOT);             // BC*1048576 ush
  unsigned short* P1  = (unsigned short*)(ws + W_TOT + (size_t)BC * 524288);
  unsigned short* P2  = P1 + (size_t)BC * 524288;
  unsigned short* P4  = P2 + (size_t)BC * 524288;
  unsigned short* Zbf = P4 + (size_t)BC * 524288;                  // unused slot
  unsigned short* Qbf = Zbf + (size_t)BC * 262144;

  init_k<<<1, 512, 0, stream>>>(hist);
  cbh_k<<<2, 256, 0, stream>>>(cb, cbh);
  repack_cbf_k<<<128, 256, 0, stream>>>(cb, cbf);

  repack_e1f_k<<<16, 256, 0, stream>>>(e1w, e1f);
  repack_pvf_k<<<32, 256, 0, stream>>>(pvw, pvf);
  repack_e2f_k<<<512, 256, 0, stream>>>(e2w, e2f);
  repack_t1f_k<<<512, 256, 0, stream>>>(t1w, t1f);
  repack_t2f_k<<<64, 256, 0, stream>>>(t2w, t2f);
  repack_frag_k<64><<<288, 256, 0, stream>>>(d1w, d1f);
  repack_frag_k<128><<<576, 256, 0, stream>>>(er11, rtf[0]);
  repack_frag_k<128><<<576, 256, 0, stream>>>(er12, rtf[1]);
  repack_frag_k<128><<<576, 256, 0, stream>>>(er21, rtf[2]);
  repack_frag_k<128><<<576, 256, 0, stream>>>(er22, rtf[3]);
  repack_frag_k<128><<<576, 256, 0, stream>>>(dr11, rtf[4]);
  repack_frag_k<128><<<576, 256, 0, stream>>>(dr12, rtf[5]);
  repack_frag_k<128><<<576, 256, 0, stream>>>(dr21, rtf[6]);
  repack_frag_k<128><<<576, 256, 0, stream>>>(dr22, rtf[7]);

  for (int c = 0; c < nchunk; ++c) {
    const float* xc = x + (size_t)c * BC * 3 * 65536;
    float* outc = out + 1 + (size_t)c * BC * 3 * 65536;
    unsigned short* bidxc = bidx + (size_t)c * BC * 4096;
    // encoder
    e1m_k<<<BC * 128, 256, 0, stream>>>(xc, e1f, e1b, E1);
    e2m_k<<<BC * 64, 256, 0, stream>>>(E1, e2f, e2b, P1);  // P1 = x0 pre-act
    // res stack 1: consumers ReLU the pre-act on the fly
    conv3nh_k<128, false, true,  false, false><<<BC * 32, 256, 0, stream>>>(P1, rtf[0], nullptr, nullptr, P4);
    conv3nh_k<128, true,  false, false, false><<<BC * 32, 256, 0, stream>>>(P4, rtf[1], nullptr, P1, P2);  // x1
    conv3nh_k<128, false, false, false, false><<<BC * 32, 256, 0, stream>>>(P2, rtf[2], nullptr, nullptr, P4);
    conv3nh_k<128, true,  false, false, false><<<BC * 32, 256, 0, stream>>>(P4, rtf[3], nullptr, P2, P1);  // x2
    // fused vector quantization: pvq conv + argmin + apply + loss partials
    vqf_k<<<BC * 16, 256, 0, stream>>>(P1, pvf, pvb, cbf, cbh, cb, Qbf, bidxc,
                                       part, c * BC * 16);
    // decoder: d1 writes pre-act only; consumer ReLUs while staging
    conv3nh_k<64,  false, false, true,  true ><<<BC * 32, 256, 0, stream>>>(Qbf, d1f, d1b, nullptr, P1);   // P1 = h pre
    conv3nh_k<128, false, true,  false, false><<<BC * 32, 256, 0, stream>>>(P1, rtf[4], nullptr, nullptr, P4);
    conv3nh_k<128, true,  false, false, false><<<BC * 32, 256, 0, stream>>>(P4, rtf[5], nullptr, P1, P2);  // h1
    conv3nh_k<128, false, false, false, false><<<BC * 32, 256, 0, stream>>>(P2, rtf[6], nullptr, nullptr, P4);
    conv3nh_k<128, true,  false, false, false><<<BC * 32, 256, 0, stream>>>(P4, rtf[7], nullptr, P2, P1);  // hres
    t1m_k<<<BC * 32, 256, 0, stream>>>(P1, t1f, t1b, E1);  // T1out overlays E1
    t2m_k<<<BC * 64, 256, 0, stream>>>(E1, t2f, t2b, outc);
  }
  vq_hist_k<<<8, 1024, 0, stream>>>(bidx, hist);
  fin_k<<<1, 512, 0, stream>>>(part, hist, out, out + 1 + 6291456);
}

// Round 15
// 866.761 us; speedup vs baseline: 1.3779x; 1.3779x over previous
//
#include <hip/hip_runtime.h>

typedef short bf16x8 __attribute__((ext_vector_type(8)));
typedef float f32x4 __attribute__((ext_vector_type(4)));
typedef unsigned short ushort4v __attribute__((ext_vector_type(4)));
typedef unsigned int u32x4 __attribute__((ext_vector_type(4)));

__device__ __forceinline__ unsigned short f2bf(float f) {
  unsigned u = __float_as_uint(f);
  unsigned r = (u + 0x7FFFu + ((u >> 16) & 1u)) >> 16;
  return (unsigned short)r;
}
__device__ __forceinline__ float bf2f(unsigned short u) {
  return __uint_as_float(((unsigned)u) << 16);
}

// packed bf16 relu: zero any 16-bit half with the sign bit set
__device__ __forceinline__ bf16x8 relu_bf8(bf16x8 v) {
  u32x4 u;
  __builtin_memcpy(&u, &v, 16);
  #pragma unroll
  for (int i = 0; i < 4; i++) {
    unsigned s = u[i] & 0x80008000u;
    u[i] &= ~((s >> 15) * 0xFFFFu);
  }
  bf16x8 r;
  __builtin_memcpy(&r, &u, 16);
  return r;
}

// XCD-aware block swizzle: consecutive logical tiles land on the same XCD's
// L2 so halo re-reads hit cache. Valid when gridDim.x % 8 == 0.
__device__ __forceinline__ int xcd_swz(int bid, int n) {
  return (bid & 7) * (n >> 3) + (bid >> 3);
}

// ---------- zero the histogram ----------
__global__ void init_k(int* __restrict__ hist) {
  int t = threadIdx.x;
  if (t < 512) hist[t] = 0;
}

// ---------- codebook half-norms ----------
__global__ void cbh_k(const float* __restrict__ cb, float* __restrict__ cbh) {
  int k = blockIdx.x * 256 + threadIdx.x;
  if (k >= 512) return;
  const float* c = cb + k * 64;
  float s = 0.f;
  #pragma unroll
  for (int d = 0; d < 64; d++) s = fmaf(c[d], c[d], s);
  cbh[k] = 0.5f * s;
}

// ---------- repack codebook (512,64) -> [m(32)][ks(2)][lane][8] bf16 ----------
__global__ void repack_cbf_k(const float* __restrict__ cb,
                             unsigned short* __restrict__ cbf) {
  int idx = blockIdx.x * 256 + threadIdx.x;
  if (idx >= 32768) return;
  int j = idx & 7;
  int lane = (idx >> 3) & 63;
  int ks = (idx >> 9) & 1;
  int m = idx >> 10;
  int code = m * 16 + (lane & 15);
  int d = ks * 32 + (lane >> 4) * 8 + j;
  cbf[idx] = f2bf(cb[code * 64 + d]);
}

// ---------- repack conv3 weights (128,CIN,3,3) -> [ks][tap][M][lane][8] bf16
template <int CIN>
__global__ void repack_frag_k(const float* __restrict__ w,
                              unsigned short* __restrict__ wf) {
  int idx = blockIdx.x * 256 + threadIdx.x;
  int total = (CIN / 32) * 9 * 8 * 512;
  if (idx >= total) return;
  int j = idx & 7;
  int lane = (idx >> 3) & 63;
  int M = (idx >> 9) & 7;
  int tk = idx >> 12;
  int tap = tk % 9;
  int kstep = tk / 9;
  int co = M * 16 + (lane & 15);
  int ci = kstep * 32 + (lane >> 4) * 8 + j;
  wf[idx] = f2bf(w[((size_t)co * CIN + ci) * 9 + tap]);
}

// ---------- repack e1 weights (64,3,4,4) -> [ks(2)][m(4)][lane][8], K pad->64
__global__ void repack_e1f_k(const float* __restrict__ w,
                             unsigned short* __restrict__ wf) {
  int idx = blockIdx.x * 256 + threadIdx.x;
  if (idx >= 4096) return;
  int j = idx & 7;
  int lane = (idx >> 3) & 63;
  int m = (idx >> 9) & 3;
  int ks = idx >> 11;
  int co = m * 16 + (lane & 15);
  int k = ks * 32 + (lane >> 4) * 8 + j;   // k = ci*16 + ky*4 + kx
  float v = (k < 48) ? w[co * 48 + k] : 0.f;
  wf[idx] = f2bf(v);
}

// ---------- repack e2 weights (128,64,4,4) -> [ks(2)][tap(16)][M(8)][lane][8]
__global__ void repack_e2f_k(const float* __restrict__ w,
                             unsigned short* __restrict__ wf) {
  int idx = blockIdx.x * 256 + threadIdx.x;
  if (idx >= 131072) return;
  int j = idx & 7;
  int lane = (idx >> 3) & 63;
  int M = (idx >> 9) & 7;
  int tap = (idx >> 12) & 15;
  int ks = idx >> 16;
  int co = M * 16 + (lane & 15);
  int ci = ks * 32 + (lane >> 4) * 8 + j;
  wf[idx] = f2bf(w[((size_t)co * 64 + ci) * 16 + tap]);
}

// ---------- repack pvq weights (64,128) -> [ks(4)][m(4)][lane][8]
__global__ void repack_pvf_k(const float* __restrict__ w,
                             unsigned short* __restrict__ wf) {
  int idx = blockIdx.x * 256 + threadIdx.x;
  if (idx >= 8192) return;
  int j = idx & 7;
  int lane = (idx >> 3) & 63;
  int m = (idx >> 9) & 3;
  int ks = idx >> 11;
  int co = m * 16 + (lane & 15);
  int ci = ks * 32 + (lane >> 4) * 8 + j;
  wf[idx] = f2bf(w[co * 128 + ci]);
}

// ---------- repack t1 weights (128,64,4,4) -> [par(4)][ks(4)][tap(4)][m(4)][lane][8]
__global__ void repack_t1f_k(const float* __restrict__ w,
                             unsigned short* __restrict__ wf) {
  int idx = blockIdx.x * 256 + threadIdx.x;
  if (idx >= 131072) return;
  int j = idx & 7;
  int lane = (idx >> 3) & 63;
  int m = (idx >> 9) & 3;
  int tap = (idx >> 11) & 3;
  int ks = (idx >> 13) & 3;
  int par = (idx >> 15) & 3;
  int sy = par >> 1, sx = par & 1;
  int ty = tap >> 1, tx = tap & 1;
  int ky = sy ? (ty ? 0 : 2) : (ty ? 1 : 3);
  int kx = sx ? (tx ? 0 : 2) : (tx ? 1 : 3);
  int co = m * 16 + (lane & 15);
  int ci = ks * 32 + (lane >> 4) * 8 + j;
  wf[idx] = f2bf(w[((size_t)ci * 64 + co) * 16 + ky * 4 + kx]);
}

// ---------- repack t2 weights (64,3,4,4) -> [par(4)][ks(2)][tap(4)][lane][8]
__global__ void repack_t2f_k(const float* __restrict__ w,
                             unsigned short* __restrict__ wf) {
  int idx = blockIdx.x * 256 + threadIdx.x;
  if (idx >= 16384) return;
  int j = idx & 7;
  int lane = (idx >> 3) & 63;
  int tap = (idx >> 9) & 3;
  int ks = (idx >> 11) & 1;
  int par = idx >> 12;
  int sy = par >> 1, sx = par & 1;
  int ty = tap >> 1, tx = tap & 1;
  int ky = sy ? (ty ? 0 : 2) : (ty ? 1 : 3);
  int kx = sx ? (tx ? 0 : 2) : (tx ? 1 : 3);
  int co = lane & 15;
  int ci = ks * 32 + (lane >> 4) * 8 + j;
  float v = (co < 3) ? w[((size_t)ci * 3 + co) * 16 + ky * 4 + kx] : 0.f;
  wf[idx] = f2bf(v);
}

// ---------- e1 via MFMA: conv 4x4 s2 p1, 3->64, bias+ReLU -> bf16 NHWC ------
__global__ __launch_bounds__(256, 4) void e1m_k(
    const float* __restrict__ x, const unsigned short* __restrict__ wf,
    const float* __restrict__ bias, unsigned short* __restrict__ out) {
  __shared__ unsigned short patch[128 * 72];
  int blk = xcd_swz(blockIdx.x, gridDim.x);
  int b = blk >> 7;
  int oy = blk & 127;
  int t = threadIdx.x;
  int w = t >> 6, l = t & 63;
  int cib = (l >> 4) * 8, colb = l & 15;
  const float* xb = x + (size_t)b * 3 * 65536;
  {
    int p = t & 127;
    int kb = (t >> 7) * 32;          // this thread stages k [kb, kb+32)
    int px2 = 2 * p - 1;
    int oy2 = 2 * oy - 1;
    bf16x8 pk[4];
    #pragma unroll
    for (int c = 0; c < 4; c++) {
      #pragma unroll
      for (int j = 0; j < 8; j++) {
        int k = kb + c * 8 + j;      // k = ci*16 + ky*4 + kx (>=48 -> pad 0)
        float v = 0.f;
        if (k < 48) {
          int ci = k >> 4;
          int ky = (k >> 2) & 3, kx = k & 3;
          int iy = oy2 + ky, ix = px2 + kx;
          if ((unsigned)iy < 256u && (unsigned)ix < 256u)
            v = xb[ci * 65536 + iy * 256 + ix];
        }
        pk[c][j] = (short)f2bf(v);
      }
    }
    unsigned short* row = &patch[p * 72 + kb];
    #pragma unroll
    for (int c = 0; c < 4; c++)
      *(bf16x8*)&row[c * 8] = pk[c];
  }
  __syncthreads();
  f32x4 acc[8];
  #pragma unroll
  for (int n = 0; n < 8; n++) acc[n] = (f32x4){0.f, 0.f, 0.f, 0.f};
  #pragma unroll
  for (int ks = 0; ks < 2; ks++) {
    bf16x8 af = *(const bf16x8*)&wf[((size_t)(ks * 4 + w) * 64 + l) * 8];
    #pragma unroll
    for (int n = 0; n < 8; n++) {
      bf16x8 bfrag =
          *(const bf16x8*)&patch[(n * 16 + colb) * 72 + ks * 32 + cib];
      acc[n] = __builtin_amdgcn_mfma_f32_16x16x32_bf16(af, bfrag, acc[n],
                                                       0, 0, 0);
    }
  }
  int cob = w * 16 + (l >> 4) * 4;
  f32x4 bj = *(const f32x4*)&bias[cob];
  #pragma unroll
  for (int n = 0; n < 8; n++) {
    int p = n * 16 + colb;
    ushort4v pk = {f2bf(fmaxf(acc[n][0] + bj[0], 0.f)),
                   f2bf(fmaxf(acc[n][1] + bj[1], 0.f)),
                   f2bf(fmaxf(acc[n][2] + bj[2], 0.f)),
                   f2bf(fmaxf(acc[n][3] + bj[3], 0.f))};
    *(ushort4v*)&out[((size_t)b * 16384 + oy * 128 + p) * 64 + cob] = pk;
  }
}

// ---------- e2 via MFMA, async-staged (global_load_lds): 4x4 s2 p1, 64->128 -
// Proven R11: LDS linear [2112 chunks][16B]; bank swizzle on GLOBAL source
// (chunk q ^ ((pos>>1)&3)); reads apply same XOR; halo lanes ds_write zeros.
__global__ __launch_bounds__(256, 4) void e2m_k(
    const unsigned short* __restrict__ in,  // bf16 NHWC (b,128,128,64)
    const unsigned short* __restrict__ wf, const float* __restrict__ bias,
    unsigned short* __restrict__ out) {     // bf16 NHWC (b,64,64,128) pre-act
  __shared__ unsigned short patch[528 * 32];
  int blk = xcd_swz(blockIdx.x, gridDim.x);
  int b = blk >> 6;
  int oy = blk & 63;
  int t = threadIdx.x;
  int w = t >> 6, l = t & 63;      // w = M-quarter: co [32w, 32w+32)
  int qr = l >> 4, colb = l & 15;
  f32x4 acc[2][4];
  #pragma unroll
  for (int m = 0; m < 2; m++)
    #pragma unroll
    for (int n = 0; n < 4; n++) acc[m][n] = (f32x4){0.f, 0.f, 0.f, 0.f};
  const unsigned short* inb = in + (size_t)b * 16384 * 64;
  for (int ks = 0; ks < 2; ks++) {
    __syncthreads();
    // async-stage 2112 chunks (4 rows x 132 cols x 4x8ci), even/odd col split
    for (int j = 0; j < 9; j++) {
      int base_chunk = j * 256 + w * 64;   // wave-uniform
      if (base_chunk >= 2112) break;
      int chunk = base_chunk + l;
      int pos = chunk >> 2, qs = chunk & 3;
      int r = pos / 132, s2 = pos - r * 132;
      int cr = (s2 < 66) ? (2 * s2) : (2 * (s2 - 66) + 1);
      int iy = 2 * oy - 1 + r, ix = cr - 1;
      int qg = qs ^ ((pos >> 1) & 3);
      if ((unsigned)iy < 128u && (unsigned)ix < 128u) {
        __builtin_amdgcn_global_load_lds(
            (const __attribute__((address_space(1))) unsigned int*)(const void*)
                &inb[((size_t)iy * 128 + ix) * 64 + ks * 32 + qg * 8],
            (__attribute__((address_space(3))) unsigned int*)(void*)
                &patch[(size_t)base_chunk * 8],
            16, 0, 0);
      } else {
        *(bf16x8*)&patch[chunk * 8] = (bf16x8){0, 0, 0, 0, 0, 0, 0, 0};
      }
    }
    __syncthreads();
    __builtin_amdgcn_s_setprio(1);
    #pragma unroll
    for (int tap = 0; tap < 16; tap++) {
      int ky = tap >> 2, kx = tap & 3;
      bf16x8 bfrag[4];
      #pragma unroll
      for (int n = 0; n < 4; n++) {
        int ox = n * 16 + colb;
        int pos = ky * 132 + (kx & 1) * 66 + ox + (kx >> 1);
        int qsl = qr ^ ((pos >> 1) & 3);
        bfrag[n] = *(const bf16x8*)&patch[pos * 32 + qsl * 8];
      }
      const unsigned short* wft = wf + ((size_t)(ks * 16 + tap) * 8) * 512;
      #pragma unroll
      for (int m = 0; m < 2; m++) {
        bf16x8 af = *(const bf16x8*)&wft[((w * 2 + m) * 64 + l) * 8];
        #pragma unroll
        for (int n = 0; n < 4; n++)
          acc[m][n] = __builtin_amdgcn_mfma_f32_16x16x32_bf16(af, bfrag[n],
                                                              acc[m][n], 0, 0, 0);
      }
    }
    __builtin_amdgcn_s_setprio(0);
  }
  #pragma unroll
  for (int m = 0; m < 2; m++) {
    int cob = (w * 2 + m) * 16 + qr * 4;
    f32x4 bj = *(const f32x4*)&bias[cob];
    #pragma unroll
    for (int n = 0; n < 4; n++) {
      int ox = n * 16 + colb;
      size_t adr = ((size_t)(b * 4096 + oy * 64 + ox)) * 128 + cob;
      ushort4v pre = {f2bf(acc[m][n][0] + bj[0]), f2bf(acc[m][n][1] + bj[1]),
                      f2bf(acc[m][n][2] + bj[2]), f2bf(acc[m][n][3] + bj[3])};
      *(ushort4v*)&out[adr] = pre;
    }
  }
}

// ---------- conv3 via MFMA, LDS-staged NHWC: 3x3 s1 p1, CIN->128 on 64x64 ---
// R11-proven form (reg-staged, BK=64 two planes, stride 36). Rule: this
// family changes only with byte-level address-pattern preservation
// (R3/R7/R12 all regressed it structurally).
template <int CIN, bool RES_ADD, bool RELU_IN, bool HAS_BIAS, bool PRE_ONLY>
__global__ __launch_bounds__(256, 4) void conv3nh_k(
    const unsigned short* __restrict__ in,   // bf16 NHWC (b,64,64,CIN)
    const unsigned short* __restrict__ wf,
    const float* __restrict__ bias,
    const unsigned short* __restrict__ res,  // bf16 NHWC (b,64,64,128) or null
    unsigned short* __restrict__ out) {      // bf16 NHWC (b,64,64,128)
  constexpr int KO = CIN / 64;               // outer K-steps (BK=64)
  __shared__ unsigned short patch[2 * 264 * 36];
  int blk = xcd_swz(blockIdx.x, gridDim.x);
  int b = blk >> 5;
  int tile = blk & 31;
  int y0 = tile * 2;
  int t = threadIdx.x;
  int w = t >> 6, l = t & 63;
  int wm = w >> 1, wn = w & 1;
  int n0 = wn * 64;
  int cib = (l >> 4) * 8, colb = l & 15;
  f32x4 acc[4][4];
  #pragma unroll
  for (int m = 0; m < 4; m++)
    #pragma unroll
    for (int n = 0; n < 4; n++) acc[m][n] = (f32x4){0.f, 0.f, 0.f, 0.f};
  const unsigned short* inb = in + (size_t)b * 4096 * CIN;
  for (int ko = 0; ko < KO; ko++) {
    __syncthreads();
    // stage 4 rows x 66 cols x 64 ci as 16B chunks into 2 planes (ksi 0/1)
    for (int idx = t; idx < 2112; idx += 256) {
      int q = idx & 7;             // 8 chunks of 8 ci = 64 ci
      int pos = idx >> 3;          // < 264
      int r = pos / 66, c = pos - r * 66;
      int y = y0 - 1 + r, x = c - 1;
      bf16x8 v = (bf16x8){0, 0, 0, 0, 0, 0, 0, 0};
      if ((unsigned)y < 64u && (unsigned)x < 64u)
        v = *(const bf16x8*)&inb[((size_t)(y * 64 + x)) * CIN + ko * 64 + q * 8];
      if (RELU_IN) v = relu_bf8(v);
      int ksi = q >> 2, qq = q & 3;
      *(bf16x8*)&patch[ksi * 9504 + pos * 36 + qq * 8] = v;
    }
    __syncthreads();
    __builtin_amdgcn_s_setprio(1);
    #pragma unroll
    for (int tap = 0; tap < 9; tap++) {
      int ky = tap / 3, kx = tap % 3;
      #pragma unroll
      for (int ksi = 0; ksi < 2; ksi++) {
        bf16x8 bfrag[4];
        #pragma unroll
        for (int n = 0; n < 4; n++) {
          int p = n0 + n * 16 + colb;
          int pr = p >> 6, pc = p & 63;
          int pos = (pr + ky) * 66 + (pc + kx);
          bfrag[n] = *(const bf16x8*)&patch[ksi * 9504 + pos * 36 + cib];
        }
        const unsigned short* wft =
            wf + (size_t)(ko * 2 + ksi) * 9 * 4096 + (size_t)tap * 4096;
        bf16x8 afrag[4];
        #pragma unroll
        for (int m = 0; m < 4; m++)
          afrag[m] = *(const bf16x8*)&wft[((wm * 4 + m) * 64 + l) * 8];
        #pragma unroll
        for (int m = 0; m < 4; m++)
          #pragma unroll
          for (int n = 0; n < 4; n++)
            acc[m][n] = __builtin_amdgcn_mfma_f32_16x16x32_bf16(
                afrag[m], bfrag[n], acc[m][n], 0, 0, 0);
      }
    }
    __builtin_amdgcn_s_setprio(0);
  }
  #pragma unroll
  for (int m = 0; m < 4; m++) {
    int cobase = wm * 64 + m * 16 + (l >> 4) * 4;
    float b0 = HAS_BIAS ? bias[cobase] : 0.f;
    float b1 = HAS_BIAS ? bias[cobase + 1] : 0.f;
    float b2 = HAS_BIAS ? bias[cobase + 2] : 0.f;
    float b3 = HAS_BIAS ? bias[cobase + 3] : 0.f;
    #pragma unroll
    for (int n = 0; n < 4; n++) {
      int p = n0 + n * 16 + colb;
      size_t adr = ((size_t)(b * 4096 + tile * 128 + p)) * 128 + cobase;
      float f0 = acc[m][n][0] + b0, f1 = acc[m][n][1] + b1;
      float f2 = acc[m][n][2] + b2, f3 = acc[m][n][3] + b3;
      if (RES_ADD) {
        ushort4v rv = *(const ushort4v*)&res[adr];
        f0 += bf2f(rv.x); f1 += bf2f(rv.y); f2 += bf2f(rv.z); f3 += bf2f(rv.w);
      }
      ushort4v pk;
      if (PRE_ONLY) {
        pk.x = f2bf(f0); pk.y = f2bf(f1); pk.z = f2bf(f2); pk.w = f2bf(f3);
      } else {
        pk.x = f2bf(fmaxf(f0, 0.f)); pk.y = f2bf(fmaxf(f1, 0.f));
        pk.z = f2bf(fmaxf(f2, 0.f)); pk.w = f2bf(fmaxf(f3, 0.f));
      }
      *(ushort4v*)&out[adr] = pk;
    }
  }
}

// ---------- fused VQ: pvq 1x1 conv -> z in LDS -> argmin -> apply + loss ----
__global__ __launch_bounds__(256, 2) void vqf_k(
    const unsigned short* __restrict__ in,  // bf16 NHWC (b,64,64,128)
    const unsigned short* __restrict__ wf, const float* __restrict__ bias,
    const unsigned short* __restrict__ cbf, const float* __restrict__ cbh,
    const float* __restrict__ cb,
    unsigned short* __restrict__ q,         // Qbf out (bf16 NHWC)
    unsigned short* __restrict__ bidx,
    float* __restrict__ part, int part_off) {
  __shared__ unsigned short zt[256 * 72];
  __shared__ unsigned short bidx_s[256];
  __shared__ float red[256];
  int blk = blockIdx.x;
  int b = blk >> 4;
  int hw0 = (blk & 15) * 256;
  int t = threadIdx.x;
  int w = t >> 6, l = t & 63;
  int n0 = w * 64;
  int cib = (l >> 4) * 8, colb = l & 15;
  // ---- phase 1: pvq 1x1 conv 128->64 + bias, z -> LDS only ----
  {
    f32x4 acc[4][4];
    #pragma unroll
    for (int m = 0; m < 4; m++)
      #pragma unroll
      for (int n = 0; n < 4; n++) acc[m][n] = (f32x4){0.f, 0.f, 0.f, 0.f};
    const unsigned short* inb = in + ((size_t)(b * 4096 + hw0)) * 128;
    for (int ks = 0; ks < 4; ks++) {
      bf16x8 bfrag[4];
      #pragma unroll
      for (int n = 0; n < 4; n++) {
        int p = n0 + n * 16 + colb;
        bfrag[n] = *(const bf16x8*)&inb[(size_t)p * 128 + ks * 32 + cib];
      }
      const unsigned short* wk = wf + ks * 4 * 512;
      #pragma unroll
      for (int m = 0; m < 4; m++) {
        bf16x8 af = *(const bf16x8*)&wk[(m * 64 + l) * 8];
        #pragma unroll
        for (int n = 0; n < 4; n++)
          acc[m][n] = __builtin_amdgcn_mfma_f32_16x16x32_bf16(af, bfrag[n],
                                                              acc[m][n], 0, 0, 0);
      }
    }
    #pragma unroll
    for (int m = 0; m < 4; m++) {
      int d0 = m * 16 + (l >> 4) * 4;
      f32x4 bj = *(const f32x4*)&bias[d0];
      #pragma unroll
      for (int n = 0; n < 4; n++) {
        int p = n0 + n * 16 + colb;
        ushort4v pk = {f2bf(acc[m][n][0] + bj[0]), f2bf(acc[m][n][1] + bj[1]),
                       f2bf(acc[m][n][2] + bj[2]), f2bf(acc[m][n][3] + bj[3])};
        *(ushort4v*)&zt[p * 72 + d0] = pk;
      }
    }
  }
  __syncthreads();
  // ---- phase 2: argmin over 512 codes via MFMA (z from LDS) ----
  {
    bf16x8 zfrag[4][2];
    #pragma unroll
    for (int n = 0; n < 4; n++) {
      int p = n0 + n * 16 + colb;
      #pragma unroll
      for (int k2 = 0; k2 < 2; k2++)
        zfrag[n][k2] = *(const bf16x8*)&zt[p * 72 + k2 * 32 + cib];
    }
    float best[4];
    int bid[4];
    #pragma unroll
    for (int n = 0; n < 4; n++) { best[n] = -1e30f; bid[n] = 0; }
    for (int m = 0; m < 32; m++) {
      bf16x8 a0 = *(const bf16x8*)&cbf[((size_t)(m * 2 + 0) * 64 + l) * 8];
      bf16x8 a1 = *(const bf16x8*)&cbf[((size_t)(m * 2 + 1) * 64 + l) * 8];
      int code0 = m * 16 + (l >> 4) * 4;
      f32x4 ch = *(const f32x4*)&cbh[code0];
      #pragma unroll
      for (int n = 0; n < 4; n++) {
        f32x4 acc2 = (f32x4){0.f, 0.f, 0.f, 0.f};
        acc2 = __builtin_amdgcn_mfma_f32_16x16x32_bf16(a0, zfrag[n][0], acc2, 0, 0, 0);
        acc2 = __builtin_amdgcn_mfma_f32_16x16x32_bf16(a1, zfrag[n][1], acc2, 0, 0, 0);
        #pragma unroll
        for (int r = 0; r < 4; r++) {
          float sc = acc2[r] - ch[r];
          if (sc > best[n]) { best[n] = sc; bid[n] = code0 + r; }
        }
      }
    }
    #pragma unroll
    for (int n = 0; n < 4; n++) {
      #pragma unroll
      for (int off = 16; off <= 32; off <<= 1) {
        float ob = __shfl_xor(best[n], off, 64);
        int oi = __shfl_xor(bid[n], off, 64);
        if (ob > best[n] || (ob == best[n] && oi < bid[n])) {
          best[n] = ob;
          bid[n] = oi;
        }
      }
      if ((l >> 4) == 0) bidx_s[n0 + n * 16 + colb] = (unsigned short)bid[n];
    }
  }
  __syncthreads();
  int bi = bidx_s[t];
  bidx[(size_t)b * 4096 + hw0 + t] = (unsigned short)bi;
  // ---- phase 3: apply (q = cb[idx]) + loss partial (z from LDS) ----
  {
    const float* cq = cb + bi * 64;
    unsigned short* qp = q + ((size_t)(b * 4096 + hw0 + t)) * 64;
    const unsigned short* zp = &zt[t * 72];
    float ls = 0.f;
    #pragma unroll
    for (int g = 0; g < 8; g++) {
      u32x4 zv = *(const u32x4*)&zp[g * 8];
      u32x4 qv;
      #pragma unroll
      for (int h = 0; h < 4; h++) {
        int d = g * 8 + h * 2;
        float q0 = cq[d], q1 = cq[d + 1];
        float z0 = __uint_as_float(zv[h] << 16);
        float z1 = __uint_as_float(zv[h] & 0xFFFF0000u);
        float d0 = q0 - z0, d1 = q1 - z1;
        ls = fmaf(d0, d0, ls);
        ls = fmaf(d1, d1, ls);
        qv[h] = (unsigned)f2bf(q0) | ((unsigned)f2bf(q1) << 16);
      }
      *(u32x4*)&qp[g * 8] = qv;
    }
    red[t] = ls;
    __syncthreads();
    for (int s = 128; s > 0; s >>= 1) {
      if (t < s) red[t] += red[t + s];
      __syncthreads();
    }
    if (t == 0) part[part_off + blk] = red[0];
  }
}

// ---------- histogram from index array ----------
__global__ __launch_bounds__(1024) void vq_hist_k(
    const unsigned short* __restrict__ bidx, int* __restrict__ hist) {
  __shared__ int hl[512];
  int t = threadIdx.x;
  if (t < 512) hl[t] = 0;
  __syncthreads();
  int base = blockIdx.x * 16384;
  for (int i = t; i < 16384; i += 1024)
    atomicAdd(&hl[bidx[base + i]], 1);
  __syncthreads();
  if (t < 512 && hl[t] > 0) atomicAdd(&hist[t], hl[t]);
}

// ---------- t1 via MFMA, async-staged NHWC: convT 4x4 s2 p1, 128->64 --------
// R15: launch_bounds (256,3). R14's (256,4) capped VGPR at 64 -> acc[4][8]
// spilled to scratch (FETCH 18.5MB->755MB, 9x slower). At 3 blocks/CU the
// cap is ~170 >= 124 live VGPRs -> no spill, +50% occupancy over (256,2).
__global__ __launch_bounds__(256, 3) void t1m_k(
    const unsigned short* __restrict__ in,  // bf16 NHWC (b,64,64,128)
    const unsigned short* __restrict__ wf, const float* __restrict__ bias,
    unsigned short* __restrict__ out) {     // bf16 NHWC (b,128,128,64)
  __shared__ unsigned short patch[1088 * 8];
  int blk = xcd_swz(blockIdx.x, gridDim.x);
  int b = blk >> 5;
  int a0 = (blk & 31) * 2;
  int t = threadIdx.x;
  int w = t >> 6, l = t & 63;
  int sy = w >> 1, sx = w & 1;
  int qr = l >> 4, colb = l & 15;
  f32x4 acc[4][8];
  #pragma unroll
  for (int m = 0; m < 4; m++)
    #pragma unroll
    for (int n = 0; n < 8; n++) acc[m][n] = (f32x4){0.f, 0.f, 0.f, 0.f};
  const unsigned short* inb = in + (size_t)b * 4096 * 128;
  for (int ks = 0; ks < 4; ks++) {
    __syncthreads();
    for (int j = 0; j < 5; j++) {
      int base_chunk = j * 256 + w * 64;   // wave-uniform
      if (base_chunk >= 1088) break;
      int chunk = base_chunk + l;
      int pos = chunk >> 2, qs = chunk & 3;
      int r = pos / 66, c = pos - r * 66;
      int y = a0 - 1 + r, x = c - 1;
      int qg = qs ^ ((pos >> 1) & 3);
      if (pos < 264 && (unsigned)y < 64u && (unsigned)x < 64u) {
        __builtin_amdgcn_global_load_lds(
            (const __attribute__((address_space(1))) unsigned int*)(const void*)
                &inb[((size_t)(y * 64 + x)) * 128 + ks * 32 + qg * 8],
            (__attribute__((address_space(3))) unsigned int*)(void*)
                &patch[(size_t)base_chunk * 8],
            16, 0, 0);
      } else {
        *(bf16x8*)&patch[chunk * 8] = (bf16x8){0, 0, 0, 0, 0, 0, 0, 0};
      }
    }
    __syncthreads();
    __builtin_amdgcn_s_setprio(1);
    const unsigned short* wpar = wf + (size_t)((sy * 2 + sx) * 4 + ks) * 8192;
    #pragma unroll
    for (int tap = 0; tap < 4; tap++) {
      int ty = tap >> 1, tx = tap & 1;
      int d = sy ? ty + 1 : ty;
      int e = sx ? tx + 1 : tx;
      bf16x8 bfrag[8];
      #pragma unroll
      for (int n = 0; n < 8; n++) {
        int p = n * 16 + colb;
        int ar = p >> 6, pc = p & 63;
        int pos = (ar + d) * 66 + (pc + e);
        int qsl = qr ^ ((pos >> 1) & 3);
        bfrag[n] = *(const bf16x8*)&patch[pos * 32 + qsl * 8];
      }
      bf16x8 afrag[4];
      #pragma unroll
      for (int m = 0; m < 4; m++)
        afrag[m] = *(const bf16x8*)&wpar[(tap * 256 + m * 64 + l) * 8];
      #pragma unroll
      for (int m = 0; m < 4; m++)
        #pragma unroll
        for (int n = 0; n < 8; n++)
          acc[m][n] = __builtin_amdgcn_mfma_f32_16x16x32_bf16(
              afrag[m], bfrag[n], acc[m][n], 0, 0, 0);
    }
    __builtin_amdgcn_s_setprio(0);
  }
  #pragma unroll
  for (int m = 0; m < 4; m++) {
    int cob = m * 16 + (l >> 4) * 4;
    float b0 = bias[cob], b1 = bias[cob + 1], b2 = bias[cob + 2],
          b3 = bias[cob + 3];
    #pragma unroll
    for (int n = 0; n < 8; n++) {
      int p = n * 16 + colb;
      int ar = p >> 6, pc = p & 63;
      int oy = 2 * (a0 + ar) + sy, ox = 2 * pc + sx;
      ushort4v pk;
      pk.x = f2bf(fmaxf(acc[m][n][0] + b0, 0.f));
      pk.y = f2bf(fmaxf(acc[m][n][1] + b1, 0.f));
      pk.z = f2bf(fmaxf(acc[m][n][2] + b2, 0.f));
      pk.w = f2bf(fmaxf(acc[m][n][3] + b3, 0.f));
      *(ushort4v*)&out[((size_t)b * 16384 + oy * 128 + ox) * 64 + cob] = pk;
    }
  }
}

// ---------- t2 via MFMA, async-staged NHWC: convT 4x4 s2 p1, 64->3 ----------
// R15: launch_bounds (256,3) — same spill-safe occupancy bump as t1m.
__global__ __launch_bounds__(256, 3) void t2m_k(
    const unsigned short* __restrict__ in,  // bf16 NHWC (b,128,128,64)
    const unsigned short* __restrict__ wf,
    const float* __restrict__ bias, float* __restrict__ out) {
  __shared__ unsigned short patch[2112 * 8];
  int blk = xcd_swz(blockIdx.x, gridDim.x);
  int b = blk >> 6;
  int a0 = (blk & 63) * 2;
  int t = threadIdx.x;
  int w = t >> 6, l = t & 63;
  int sy = w >> 1, sx = w & 1;
  int qr = l >> 4, colb = l & 15;
  f32x4 acc[2][8];
  #pragma unroll
  for (int ar = 0; ar < 2; ar++)
    #pragma unroll
    for (int n = 0; n < 8; n++) acc[ar][n] = (f32x4){0.f, 0.f, 0.f, 0.f};
  bf16x8 af[2][4];
  #pragma unroll
  for (int ks = 0; ks < 2; ks++) {
    const unsigned short* wpar = wf + (size_t)((sy * 2 + sx) * 2 + ks) * 2048;
    #pragma unroll
    for (int tap = 0; tap < 4; tap++)
      af[ks][tap] = *(const bf16x8*)&wpar[(tap * 64 + l) * 8];
  }
  const unsigned short* inb = in + (size_t)b * 16384 * 64;
  for (int ks = 0; ks < 2; ks++) {
    __syncthreads();
    for (int j = 0; j < 9; j++) {
      int base_chunk = j * 256 + w * 64;   // wave-uniform
      if (base_chunk >= 2112) break;
      int chunk = base_chunk + l;
      int pos = chunk >> 2, qs = chunk & 3;
      int r = pos / 132, c = pos - r * 132;
      int y = a0 - 1 + r, x = c - 1;
      int qg = qs ^ ((pos >> 1) & 3);
      if ((unsigned)y < 128u && (unsigned)x < 128u) {
        __builtin_amdgcn_global_load_lds(
            (const __attribute__((address_space(1))) unsigned int*)(const void*)
                &inb[((size_t)(y * 128 + x)) * 64 + ks * 32 + qg * 8],
            (__attribute__((address_space(3))) unsigned int*)(void*)
                &patch[(size_t)base_chunk * 8],
            16, 0, 0);
      } else {
        *(bf16x8*)&patch[chunk * 8] = (bf16x8){0, 0, 0, 0, 0, 0, 0, 0};
      }
    }
    __syncthreads();
    __builtin_amdgcn_s_setprio(1);
    #pragma unroll
    for (int tap = 0; tap < 4; tap++) {
      int ty = tap >> 1, tx = tap & 1;
      int d = sy ? ty + 1 : ty;
      int e = sx ? tx + 1 : tx;
      #pragma unroll
      for (int ar = 0; ar < 2; ar++) {
        #pragma unroll
        for (int n = 0; n < 8; n++) {
          int pc = n * 16 + colb;
          int pos = (ar + d) * 132 + (pc + e);
          int qsl = qr ^ ((pos >> 1) & 3);
          bf16x8 bfrag = *(const bf16x8*)&patch[pos * 32 + qsl * 8];
          acc[ar][n] = __builtin_amdgcn_mfma_f32_16x16x32_bf16(
              af[ks][tap], bfrag, acc[ar][n], 0, 0, 0);
        }
      }
    }
    __builtin_amdgcn_s_setprio(0);
  }
  int rb = (l >> 4) * 4;
  #pragma unroll
  for (int r = 0; r < 4; r++) {
    int co = rb + r;
    if (co < 3) {
      float bj = bias[co];
      #pragma unroll
      for (int ar = 0; ar < 2; ar++) {
        int oy = 2 * (a0 + ar) + sy;
        #pragma unroll
        for (int n = 0; n < 8; n++) {
          int pc = n * 16 + colb;
          int ox = 2 * pc + sx;
          out[((size_t)(b * 3 + co)) * 65536 + oy * 256 + ox] = acc[ar][n][r] + bj;
        }
      }
    }
  }
}

// ---------- finalize: loss + perplexity ----------
__global__ __launch_bounds__(512) void fin_k(
    const float* __restrict__ part, const int* __restrict__ hist,
    float* __restrict__ loss_out, float* __restrict__ perp_out) {
  __shared__ float red[512];
  int t = threadIdx.x;
  red[t] = part[t];
  __syncthreads();
  for (int s = 256; s > 0; s >>= 1) {
    if (t < s) red[t] += red[t + s];
    __syncthreads();
  }
  float loss = 1.25f * red[0] / 8388608.f;
  __syncthreads();
  float p = (float)hist[t] / 131072.f;
  red[t] = -p * logf(p + 1e-10f);
  __syncthreads();
  for (int s = 256; s > 0; s >>= 1) {
    if (t < s) red[t] += red[t + s];
    __syncthreads();
  }
  if (t == 0) {
    *loss_out = loss;
    *perp_out = expf(red[0]);
  }
}

// ---------------------------------------------------------------------------
extern "C" void kernel_launch(void* const* d_in, const int* in_sizes, int n_in,
                              void* d_out, int out_size, void* d_ws, size_t ws_size,
                              hipStream_t stream) {
  (void)in_sizes; (void)n_in; (void)out_size;
  const float* x    = (const float*)d_in[0];
  const float* e1w  = (const float*)d_in[1];
  const float* e1b  = (const float*)d_in[2];
  const float* e2w  = (const float*)d_in[3];
  const float* e2b  = (const float*)d_in[4];
  const float* er11 = (const float*)d_in[5];
  const float* er12 = (const float*)d_in[6];
  const float* er21 = (const float*)d_in[7];
  const float* er22 = (const float*)d_in[8];
  const float* pvw  = (const float*)d_in[9];
  const float* pvb  = (const float*)d_in[10];
  const float* cb   = (const float*)d_in[11];
  const float* d1w  = (const float*)d_in[12];
  const float* d1b  = (const float*)d_in[13];
  const float* dr11 = (const float*)d_in[14];
  const float* dr12 = (const float*)d_in[15];
  const float* dr21 = (const float*)d_in[16];
  const float* dr22 = (const float*)d_in[17];
  const float* t1w  = (const float*)d_in[18];
  const float* t1b  = (const float*)d_in[19];
  const float* t2w  = (const float*)d_in[20];
  const float* t2b  = (const float*)d_in[21];
  float* out = (float*)d_out;

  // ---- workspace layout (float offsets) ----
  const size_t W_PVF  = 0;
  const size_t W_E2F  = W_PVF + 4096;
  const size_t W_T1F  = W_E2F + 65536;
  const size_t W_T2F  = W_T1F + 65536;
  const size_t W_D1F  = W_T2F + 8192;
  const size_t W_CBF  = W_D1F + 36864;
  const size_t W_E1F  = W_CBF + 16384;
  const size_t W_RT   = W_E1F + 2048;
  const size_t W_CBH  = W_RT + 8 * 73728;
  const size_t W_PART = W_CBH + 512;
  const size_t W_BIDX = W_PART + 512;
  const size_t W_HIST = W_BIDX + 65536;
  const size_t W_TOT  = W_HIST + 512;

  float* ws = (float*)d_ws;
  unsigned short* pvf = (unsigned short*)(ws + W_PVF);
  unsigned short* e2f = (unsigned short*)(ws + W_E2F);
  unsigned short* t1f = (unsigned short*)(ws + W_T1F);
  unsigned short* t2f = (unsigned short*)(ws + W_T2F);
  unsigned short* d1f = (unsigned short*)(ws + W_D1F);
  unsigned short* cbf = (unsigned short*)(ws + W_CBF);
  unsigned short* e1f = (unsigned short*)(ws + W_E1F);
  unsigned short* rtf[8];
  for (int i = 0; i < 8; i++)
    rtf[i] = (unsigned short*)(ws + W_RT + (size_t)i * 73728);
  float* cbh  = ws + W_CBH;
  float* part = ws + W_PART;
  unsigned short* bidx = (unsigned short*)(ws + W_BIDX);
  int*   hist = (int*)(ws + W_HIST);

  size_t wfloats = ws_size / sizeof(float);
  int BC = 32;
  while (BC > 1 && W_TOT + (size_t)BC * 1572864 > wfloats) BC >>= 1;
  int nchunk = 32 / BC;

  // dynamic buffers (bf16 NHWC): E1/T1 (overlaid), P1, P2, P4, Zbf, Qbf
  unsigned short* E1  = (unsigned short*)(ws + W_TOT);             // BC*1048576 ush
  unsigned short* P1  = (unsigned short*)(ws + W_TOT + (size_t)BC * 524288);
  unsigned short* P2  = P1 + (size_t)BC * 524288;
  unsigned short* P4  = P2 + (size_t)BC * 524288;
  unsigned short* Zbf = P4 + (size_t)BC * 524288;                  // unused slot
  unsigned short* Qbf = Zbf + (size_t)BC * 262144;

  init_k<<<1, 512, 0, stream>>>(hist);
  cbh_k<<<2, 256, 0, stream>>>(cb, cbh);
  repack_cbf_k<<<128, 256, 0, stream>>>(cb, cbf);

  repack_e1f_k<<<16, 256, 0, stream>>>(e1w, e1f);
  repack_pvf_k<<<32, 256, 0, stream>>>(pvw, pvf);
  repack_e2f_k<<<512, 256, 0, stream>>>(e2w, e2f);
  repack_t1f_k<<<512, 256, 0, stream>>>(t1w, t1f);
  repack_t2f_k<<<64, 256, 0, stream>>>(t2w, t2f);
  repack_frag_k<64><<<288, 256, 0, stream>>>(d1w, d1f);
  repack_frag_k<128><<<576, 256, 0, stream>>>(er11, rtf[0]);
  repack_frag_k<128><<<576, 256, 0, stream>>>(er12, rtf[1]);
  repack_frag_k<128><<<576, 256, 0, stream>>>(er21, rtf[2]);
  repack_frag_k<128><<<576, 256, 0, stream>>>(er22, rtf[3]);
  repack_frag_k<128><<<576, 256, 0, stream>>>(dr11, rtf[4]);
  repack_frag_k<128><<<576, 256, 0, stream>>>(dr12, rtf[5]);
  repack_frag_k<128><<<576, 256, 0, stream>>>(dr21, rtf[6]);
  repack_frag_k<128><<<576, 256, 0, stream>>>(dr22, rtf[7]);

  for (int c = 0; c < nchunk; ++c) {
    const float* xc = x + (size_t)c * BC * 3 * 65536;
    float* outc = out + 1 + (size_t)c * BC * 3 * 65536;
    unsigned short* bidxc = bidx + (size_t)c * BC * 4096;
    // encoder
    e1m_k<<<BC * 128, 256, 0, stream>>>(xc, e1f, e1b, E1);
    e2m_k<<<BC * 64, 256, 0, stream>>>(E1, e2f, e2b, P1);  // P1 = x0 pre-act
    // res stack 1: consumers ReLU the pre-act on the fly
    conv3nh_k<128, false, true,  false, false><<<BC * 32, 256, 0, stream>>>(P1, rtf[0], nullptr, nullptr, P4);
    conv3nh_k<128, true,  false, false, false><<<BC * 32, 256, 0, stream>>>(P4, rtf[1], nullptr, P1, P2);  // x1
    conv3nh_k<128, false, false, false, false><<<BC * 32, 256, 0, stream>>>(P2, rtf[2], nullptr, nullptr, P4);
    conv3nh_k<128, true,  false, false, false><<<BC * 32, 256, 0, stream>>>(P4, rtf[3], nullptr, P2, P1);  // x2
    // fused vector quantization: pvq conv + argmin + apply + loss partials
    vqf_k<<<BC * 16, 256, 0, stream>>>(P1, pvf, pvb, cbf, cbh, cb, Qbf, bidxc,
                                       part, c * BC * 16);
    // decoder: d1 writes pre-act only; consumer ReLUs while staging
    conv3nh_k<64,  false, false, true,  true ><<<BC * 32, 256, 0, stream>>>(Qbf, d1f, d1b, nullptr, P1);   // P1 = h pre
    conv3nh_k<128, false, true,  false, false><<<BC * 32, 256, 0, stream>>>(P1, rtf[4], nullptr, nullptr, P4);
    conv3nh_k<128, true,  false, false, false><<<BC * 32, 256, 0, stream>>>(P4, rtf[5], nullptr, P1, P2);  // h1
    conv3nh_k<128, false, false, false, false><<<BC * 32, 256, 0, stream>>>(P2, rtf[6], nullptr, nullptr, P4);
    conv3nh_k<128, true,  false, false, false><<<BC * 32, 256, 0, stream>>>(P4, rtf[7], nullptr, P2, P1);  // hres
    t1m_k<<<BC * 32, 256, 0, stream>>>(P1, t1f, t1b, E1);  // T1out overlays E1
    t2m_k<<<BC * 64, 256, 0, stream>>>(E1, t2f, t2b, outc);
  }
  vq_hist_k<<<8, 1024, 0, stream>>>(bidx, hist);
  fin_k<<<1, 512, 0, stream>>>(part, hist, out, out + 1 + 6291456);
}

// Round 16
// 596.553 us; speedup vs baseline: 2.0020x; 1.4529x over previous
//
#include <hip/hip_runtime.h>

typedef short bf16x8 __attribute__((ext_vector_type(8)));
typedef float f32x4 __attribute__((ext_vector_type(4)));
typedef unsigned short ushort4v __attribute__((ext_vector_type(4)));
typedef unsigned int u32x4 __attribute__((ext_vector_type(4)));

__device__ __forceinline__ unsigned short f2bf(float f) {
  unsigned u = __float_as_uint(f);
  unsigned r = (u + 0x7FFFu + ((u >> 16) & 1u)) >> 16;
  return (unsigned short)r;
}
__device__ __forceinline__ float bf2f(unsigned short u) {
  return __uint_as_float(((unsigned)u) << 16);
}

// packed bf16 relu: zero any 16-bit half with the sign bit set
__device__ __forceinline__ bf16x8 relu_bf8(bf16x8 v) {
  u32x4 u;
  __builtin_memcpy(&u, &v, 16);
  #pragma unroll
  for (int i = 0; i < 4; i++) {
    unsigned s = u[i] & 0x80008000u;
    u[i] &= ~((s >> 15) * 0xFFFFu);
  }
  bf16x8 r;
  __builtin_memcpy(&r, &u, 16);
  return r;
}

// XCD-aware block swizzle: consecutive logical tiles land on the same XCD's
// L2 so halo re-reads hit cache. Valid when gridDim.x % 8 == 0.
__device__ __forceinline__ int xcd_swz(int bid, int n) {
  return (bid & 7) * (n >> 3) + (bid >> 3);
}

// ---------- zero the histogram ----------
__global__ void init_k(int* __restrict__ hist) {
  int t = threadIdx.x;
  if (t < 512) hist[t] = 0;
}

// ---------- codebook half-norms ----------
__global__ void cbh_k(const float* __restrict__ cb, float* __restrict__ cbh) {
  int k = blockIdx.x * 256 + threadIdx.x;
  if (k >= 512) return;
  const float* c = cb + k * 64;
  float s = 0.f;
  #pragma unroll
  for (int d = 0; d < 64; d++) s = fmaf(c[d], c[d], s);
  cbh[k] = 0.5f * s;
}

// ---------- repack codebook (512,64) -> [m(32)][ks(2)][lane][8] bf16 ----------
__global__ void repack_cbf_k(const float* __restrict__ cb,
                             unsigned short* __restrict__ cbf) {
  int idx = blockIdx.x * 256 + threadIdx.x;
  if (idx >= 32768) return;
  int j = idx & 7;
  int lane = (idx >> 3) & 63;
  int ks = (idx >> 9) & 1;
  int m = idx >> 10;
  int code = m * 16 + (lane & 15);
  int d = ks * 32 + (lane >> 4) * 8 + j;
  cbf[idx] = f2bf(cb[code * 64 + d]);
}

// ---------- repack conv3 weights (128,CIN,3,3) -> [ks][tap][M][lane][8] bf16
template <int CIN>
__global__ void repack_frag_k(const float* __restrict__ w,
                              unsigned short* __restrict__ wf) {
  int idx = blockIdx.x * 256 + threadIdx.x;
  int total = (CIN / 32) * 9 * 8 * 512;
  if (idx >= total) return;
  int j = idx & 7;
  int lane = (idx >> 3) & 63;
  int M = (idx >> 9) & 7;
  int tk = idx >> 12;
  int tap = tk % 9;
  int kstep = tk / 9;
  int co = M * 16 + (lane & 15);
  int ci = kstep * 32 + (lane >> 4) * 8 + j;
  wf[idx] = f2bf(w[((size_t)co * CIN + ci) * 9 + tap]);
}

// ---------- repack e1 weights (64,3,4,4) -> [ks(2)][m(4)][lane][8], K pad->64
__global__ void repack_e1f_k(const float* __restrict__ w,
                             unsigned short* __restrict__ wf) {
  int idx = blockIdx.x * 256 + threadIdx.x;
  if (idx >= 4096) return;
  int j = idx & 7;
  int lane = (idx >> 3) & 63;
  int m = (idx >> 9) & 3;
  int ks = idx >> 11;
  int co = m * 16 + (lane & 15);
  int k = ks * 32 + (lane >> 4) * 8 + j;   // k = ci*16 + ky*4 + kx
  float v = (k < 48) ? w[co * 48 + k] : 0.f;
  wf[idx] = f2bf(v);
}

// ---------- repack e2 weights (128,64,4,4) -> [ks(2)][tap(16)][M(8)][lane][8]
__global__ void repack_e2f_k(const float* __restrict__ w,
                             unsigned short* __restrict__ wf) {
  int idx = blockIdx.x * 256 + threadIdx.x;
  if (idx >= 131072) return;
  int j = idx & 7;
  int lane = (idx >> 3) & 63;
  int M = (idx >> 9) & 7;
  int tap = (idx >> 12) & 15;
  int ks = idx >> 16;
  int co = M * 16 + (lane & 15);
  int ci = ks * 32 + (lane >> 4) * 8 + j;
  wf[idx] = f2bf(w[((size_t)co * 64 + ci) * 16 + tap]);
}

// ---------- repack pvq weights (64,128) -> [ks(4)][m(4)][lane][8]
__global__ void repack_pvf_k(const float* __restrict__ w,
                             unsigned short* __restrict__ wf) {
  int idx = blockIdx.x * 256 + threadIdx.x;
  if (idx >= 8192) return;
  int j = idx & 7;
  int lane = (idx >> 3) & 63;
  int m = (idx >> 9) & 3;
  int ks = idx >> 11;
  int co = m * 16 + (lane & 15);
  int ci = ks * 32 + (lane >> 4) * 8 + j;
  wf[idx] = f2bf(w[co * 128 + ci]);
}

// ---------- repack t1 weights (128,64,4,4) -> [par(4)][ks(4)][tap(4)][m(4)][lane][8]
__global__ void repack_t1f_k(const float* __restrict__ w,
                             unsigned short* __restrict__ wf) {
  int idx = blockIdx.x * 256 + threadIdx.x;
  if (idx >= 131072) return;
  int j = idx & 7;
  int lane = (idx >> 3) & 63;
  int m = (idx >> 9) & 3;
  int tap = (idx >> 11) & 3;
  int ks = (idx >> 13) & 3;
  int par = (idx >> 15) & 3;
  int sy = par >> 1, sx = par & 1;
  int ty = tap >> 1, tx = tap & 1;
  int ky = sy ? (ty ? 0 : 2) : (ty ? 1 : 3);
  int kx = sx ? (tx ? 0 : 2) : (tx ? 1 : 3);
  int co = m * 16 + (lane & 15);
  int ci = ks * 32 + (lane >> 4) * 8 + j;
  wf[idx] = f2bf(w[((size_t)ci * 64 + co) * 16 + ky * 4 + kx]);
}

// ---------- repack t2 weights (64,3,4,4) -> [par(4)][ks(2)][tap(4)][lane][8]
__global__ void repack_t2f_k(const float* __restrict__ w,
                             unsigned short* __restrict__ wf) {
  int idx = blockIdx.x * 256 + threadIdx.x;
  if (idx >= 16384) return;
  int j = idx & 7;
  int lane = (idx >> 3) & 63;
  int tap = (idx >> 9) & 3;
  int ks = (idx >> 11) & 1;
  int par = idx >> 12;
  int sy = par >> 1, sx = par & 1;
  int ty = tap >> 1, tx = tap & 1;
  int ky = sy ? (ty ? 0 : 2) : (ty ? 1 : 3);
  int kx = sx ? (tx ? 0 : 2) : (tx ? 1 : 3);
  int co = lane & 15;
  int ci = ks * 32 + (lane >> 4) * 8 + j;
  float v = (co < 3) ? w[((size_t)ci * 3 + co) * 16 + ky * 4 + kx] : 0.f;
  wf[idx] = f2bf(v);
}

// ---------- e1 via MFMA: conv 4x4 s2 p1, 3->64, bias+ReLU -> bf16 NHWC ------
__global__ __launch_bounds__(256, 4) void e1m_k(
    const float* __restrict__ x, const unsigned short* __restrict__ wf,
    const float* __restrict__ bias, unsigned short* __restrict__ out) {
  __shared__ unsigned short patch[128 * 72];
  int blk = xcd_swz(blockIdx.x, gridDim.x);
  int b = blk >> 7;
  int oy = blk & 127;
  int t = threadIdx.x;
  int w = t >> 6, l = t & 63;
  int cib = (l >> 4) * 8, colb = l & 15;
  const float* xb = x + (size_t)b * 3 * 65536;
  {
    int p = t & 127;
    int kb = (t >> 7) * 32;          // this thread stages k [kb, kb+32)
    int px2 = 2 * p - 1;
    int oy2 = 2 * oy - 1;
    bf16x8 pk[4];
    #pragma unroll
    for (int c = 0; c < 4; c++) {
      #pragma unroll
      for (int j = 0; j < 8; j++) {
        int k = kb + c * 8 + j;      // k = ci*16 + ky*4 + kx (>=48 -> pad 0)
        float v = 0.f;
        if (k < 48) {
          int ci = k >> 4;
          int ky = (k >> 2) & 3, kx = k & 3;
          int iy = oy2 + ky, ix = px2 + kx;
          if ((unsigned)iy < 256u && (unsigned)ix < 256u)
            v = xb[ci * 65536 + iy * 256 + ix];
        }
        pk[c][j] = (short)f2bf(v);
      }
    }
    unsigned short* row = &patch[p * 72 + kb];
    #pragma unroll
    for (int c = 0; c < 4; c++)
      *(bf16x8*)&row[c * 8] = pk[c];
  }
  __syncthreads();
  f32x4 acc[8];
  #pragma unroll
  for (int n = 0; n < 8; n++) acc[n] = (f32x4){0.f, 0.f, 0.f, 0.f};
  #pragma unroll
  for (int ks = 0; ks < 2; ks++) {
    bf16x8 af = *(const bf16x8*)&wf[((size_t)(ks * 4 + w) * 64 + l) * 8];
    #pragma unroll
    for (int n = 0; n < 8; n++) {
      bf16x8 bfrag =
          *(const bf16x8*)&patch[(n * 16 + colb) * 72 + ks * 32 + cib];
      acc[n] = __builtin_amdgcn_mfma_f32_16x16x32_bf16(af, bfrag, acc[n],
                                                       0, 0, 0);
    }
  }
  int cob = w * 16 + (l >> 4) * 4;
  f32x4 bj = *(const f32x4*)&bias[cob];
  #pragma unroll
  for (int n = 0; n < 8; n++) {
    int p = n * 16 + colb;
    ushort4v pk = {f2bf(fmaxf(acc[n][0] + bj[0], 0.f)),
                   f2bf(fmaxf(acc[n][1] + bj[1], 0.f)),
                   f2bf(fmaxf(acc[n][2] + bj[2], 0.f)),
                   f2bf(fmaxf(acc[n][3] + bj[3], 0.f))};
    *(ushort4v*)&out[((size_t)b * 16384 + oy * 128 + p) * 64 + cob] = pk;
  }
}

// ---------- e2 via MFMA, async-staged (global_load_lds): 4x4 s2 p1, 64->128 -
// Proven R11: LDS linear [2112 chunks][16B]; bank swizzle on GLOBAL source
// (chunk q ^ ((pos>>1)&3)); reads apply same XOR; halo lanes ds_write zeros.
__global__ __launch_bounds__(256, 4) void e2m_k(
    const unsigned short* __restrict__ in,  // bf16 NHWC (b,128,128,64)
    const unsigned short* __restrict__ wf, const float* __restrict__ bias,
    unsigned short* __restrict__ out) {     // bf16 NHWC (b,64,64,128) pre-act
  __shared__ unsigned short patch[528 * 32];
  int blk = xcd_swz(blockIdx.x, gridDim.x);
  int b = blk >> 6;
  int oy = blk & 63;
  int t = threadIdx.x;
  int w = t >> 6, l = t & 63;      // w = M-quarter: co [32w, 32w+32)
  int qr = l >> 4, colb = l & 15;
  f32x4 acc[2][4];
  #pragma unroll
  for (int m = 0; m < 2; m++)
    #pragma unroll
    for (int n = 0; n < 4; n++) acc[m][n] = (f32x4){0.f, 0.f, 0.f, 0.f};
  const unsigned short* inb = in + (size_t)b * 16384 * 64;
  for (int ks = 0; ks < 2; ks++) {
    __syncthreads();
    // async-stage 2112 chunks (4 rows x 132 cols x 4x8ci), even/odd col split
    for (int j = 0; j < 9; j++) {
      int base_chunk = j * 256 + w * 64;   // wave-uniform
      if (base_chunk >= 2112) break;
      int chunk = base_chunk + l;
      int pos = chunk >> 2, qs = chunk & 3;
      int r = pos / 132, s2 = pos - r * 132;
      int cr = (s2 < 66) ? (2 * s2) : (2 * (s2 - 66) + 1);
      int iy = 2 * oy - 1 + r, ix = cr - 1;
      int qg = qs ^ ((pos >> 1) & 3);
      if ((unsigned)iy < 128u && (unsigned)ix < 128u) {
        __builtin_amdgcn_global_load_lds(
            (const __attribute__((address_space(1))) unsigned int*)(const void*)
                &inb[((size_t)iy * 128 + ix) * 64 + ks * 32 + qg * 8],
            (__attribute__((address_space(3))) unsigned int*)(void*)
                &patch[(size_t)base_chunk * 8],
            16, 0, 0);
      } else {
        *(bf16x8*)&patch[chunk * 8] = (bf16x8){0, 0, 0, 0, 0, 0, 0, 0};
      }
    }
    __syncthreads();
    __builtin_amdgcn_s_setprio(1);
    #pragma unroll
    for (int tap = 0; tap < 16; tap++) {
      int ky = tap >> 2, kx = tap & 3;
      bf16x8 bfrag[4];
      #pragma unroll
      for (int n = 0; n < 4; n++) {
        int ox = n * 16 + colb;
        int pos = ky * 132 + (kx & 1) * 66 + ox + (kx >> 1);
        int qsl = qr ^ ((pos >> 1) & 3);
        bfrag[n] = *(const bf16x8*)&patch[pos * 32 + qsl * 8];
      }
      const unsigned short* wft = wf + ((size_t)(ks * 16 + tap) * 8) * 512;
      #pragma unroll
      for (int m = 0; m < 2; m++) {
        bf16x8 af = *(const bf16x8*)&wft[((w * 2 + m) * 64 + l) * 8];
        #pragma unroll
        for (int n = 0; n < 4; n++)
          acc[m][n] = __builtin_amdgcn_mfma_f32_16x16x32_bf16(af, bfrag[n],
                                                              acc[m][n], 0, 0, 0);
      }
    }
    __builtin_amdgcn_s_setprio(0);
  }
  #pragma unroll
  for (int m = 0; m < 2; m++) {
    int cob = (w * 2 + m) * 16 + qr * 4;
    f32x4 bj = *(const f32x4*)&bias[cob];
    #pragma unroll
    for (int n = 0; n < 4; n++) {
      int ox = n * 16 + colb;
      size_t adr = ((size_t)(b * 4096 + oy * 64 + ox)) * 128 + cob;
      ushort4v pre = {f2bf(acc[m][n][0] + bj[0]), f2bf(acc[m][n][1] + bj[1]),
                      f2bf(acc[m][n][2] + bj[2]), f2bf(acc[m][n][3] + bj[3])};
      *(ushort4v*)&out[adr] = pre;
    }
  }
}

// ---------- conv3 via MFMA, LDS-staged NHWC: 3x3 s1 p1, CIN->128 on 64x64 ---
// R11-proven form (reg-staged, BK=64 two planes, stride 36). Rule: this
// family changes only with byte-level address-pattern preservation
// (R3/R7/R12 all regressed it structurally).
template <int CIN, bool RES_ADD, bool RELU_IN, bool HAS_BIAS, bool PRE_ONLY>
__global__ __launch_bounds__(256, 4) void conv3nh_k(
    const unsigned short* __restrict__ in,   // bf16 NHWC (b,64,64,CIN)
    const unsigned short* __restrict__ wf,
    const float* __restrict__ bias,
    const unsigned short* __restrict__ res,  // bf16 NHWC (b,64,64,128) or null
    unsigned short* __restrict__ out) {      // bf16 NHWC (b,64,64,128)
  constexpr int KO = CIN / 64;               // outer K-steps (BK=64)
  __shared__ unsigned short patch[2 * 264 * 36];
  int blk = xcd_swz(blockIdx.x, gridDim.x);
  int b = blk >> 5;
  int tile = blk & 31;
  int y0 = tile * 2;
  int t = threadIdx.x;
  int w = t >> 6, l = t & 63;
  int wm = w >> 1, wn = w & 1;
  int n0 = wn * 64;
  int cib = (l >> 4) * 8, colb = l & 15;
  f32x4 acc[4][4];
  #pragma unroll
  for (int m = 0; m < 4; m++)
    #pragma unroll
    for (int n = 0; n < 4; n++) acc[m][n] = (f32x4){0.f, 0.f, 0.f, 0.f};
  const unsigned short* inb = in + (size_t)b * 4096 * CIN;
  for (int ko = 0; ko < KO; ko++) {
    __syncthreads();
    // stage 4 rows x 66 cols x 64 ci as 16B chunks into 2 planes (ksi 0/1)
    for (int idx = t; idx < 2112; idx += 256) {
      int q = idx & 7;             // 8 chunks of 8 ci = 64 ci
      int pos = idx >> 3;          // < 264
      int r = pos / 66, c = pos - r * 66;
      int y = y0 - 1 + r, x = c - 1;
      bf16x8 v = (bf16x8){0, 0, 0, 0, 0, 0, 0, 0};
      if ((unsigned)y < 64u && (unsigned)x < 64u)
        v = *(const bf16x8*)&inb[((size_t)(y * 64 + x)) * CIN + ko * 64 + q * 8];
      if (RELU_IN) v = relu_bf8(v);
      int ksi = q >> 2, qq = q & 3;
      *(bf16x8*)&patch[ksi * 9504 + pos * 36 + qq * 8] = v;
    }
    __syncthreads();
    __builtin_amdgcn_s_setprio(1);
    #pragma unroll
    for (int tap = 0; tap < 9; tap++) {
      int ky = tap / 3, kx = tap % 3;
      #pragma unroll
      for (int ksi = 0; ksi < 2; ksi++) {
        bf16x8 bfrag[4];
        #pragma unroll
        for (int n = 0; n < 4; n++) {
          int p = n0 + n * 16 + colb;
          int pr = p >> 6, pc = p & 63;
          int pos = (pr + ky) * 66 + (pc + kx);
          bfrag[n] = *(const bf16x8*)&patch[ksi * 9504 + pos * 36 + cib];
        }
        const unsigned short* wft =
            wf + (size_t)(ko * 2 + ksi) * 9 * 4096 + (size_t)tap * 4096;
        bf16x8 afrag[4];
        #pragma unroll
        for (int m = 0; m < 4; m++)
          afrag[m] = *(const bf16x8*)&wft[((wm * 4 + m) * 64 + l) * 8];
        #pragma unroll
        for (int m = 0; m < 4; m++)
          #pragma unroll
          for (int n = 0; n < 4; n++)
            acc[m][n] = __builtin_amdgcn_mfma_f32_16x16x32_bf16(
                afrag[m], bfrag[n], acc[m][n], 0, 0, 0);
      }
    }
    __builtin_amdgcn_s_setprio(0);
  }
  #pragma unroll
  for (int m = 0; m < 4; m++) {
    int cobase = wm * 64 + m * 16 + (l >> 4) * 4;
    float b0 = HAS_BIAS ? bias[cobase] : 0.f;
    float b1 = HAS_BIAS ? bias[cobase + 1] : 0.f;
    float b2 = HAS_BIAS ? bias[cobase + 2] : 0.f;
    float b3 = HAS_BIAS ? bias[cobase + 3] : 0.f;
    #pragma unroll
    for (int n = 0; n < 4; n++) {
      int p = n0 + n * 16 + colb;
      size_t adr = ((size_t)(b * 4096 + tile * 128 + p)) * 128 + cobase;
      float f0 = acc[m][n][0] + b0, f1 = acc[m][n][1] + b1;
      float f2 = acc[m][n][2] + b2, f3 = acc[m][n][3] + b3;
      if (RES_ADD) {
        ushort4v rv = *(const ushort4v*)&res[adr];
        f0 += bf2f(rv.x); f1 += bf2f(rv.y); f2 += bf2f(rv.z); f3 += bf2f(rv.w);
      }
      ushort4v pk;
      if (PRE_ONLY) {
        pk.x = f2bf(f0); pk.y = f2bf(f1); pk.z = f2bf(f2); pk.w = f2bf(f3);
      } else {
        pk.x = f2bf(fmaxf(f0, 0.f)); pk.y = f2bf(fmaxf(f1, 0.f));
        pk.z = f2bf(fmaxf(f2, 0.f)); pk.w = f2bf(fmaxf(f3, 0.f));
      }
      *(ushort4v*)&out[adr] = pk;
    }
  }
}

// ---------- fused VQ: pvq 1x1 conv -> z in LDS -> argmin -> apply + loss ----
__global__ __launch_bounds__(256, 2) void vqf_k(
    const unsigned short* __restrict__ in,  // bf16 NHWC (b,64,64,128)
    const unsigned short* __restrict__ wf, const float* __restrict__ bias,
    const unsigned short* __restrict__ cbf, const float* __restrict__ cbh,
    const float* __restrict__ cb,
    unsigned short* __restrict__ q,         // Qbf out (bf16 NHWC)
    unsigned short* __restrict__ bidx,
    float* __restrict__ part, int part_off) {
  __shared__ unsigned short zt[256 * 72];
  __shared__ unsigned short bidx_s[256];
  __shared__ float red[256];
  int blk = blockIdx.x;
  int b = blk >> 4;
  int hw0 = (blk & 15) * 256;
  int t = threadIdx.x;
  int w = t >> 6, l = t & 63;
  int n0 = w * 64;
  int cib = (l >> 4) * 8, colb = l & 15;
  // ---- phase 1: pvq 1x1 conv 128->64 + bias, z -> LDS only ----
  {
    f32x4 acc[4][4];
    #pragma unroll
    for (int m = 0; m < 4; m++)
      #pragma unroll
      for (int n = 0; n < 4; n++) acc[m][n] = (f32x4){0.f, 0.f, 0.f, 0.f};
    const unsigned short* inb = in + ((size_t)(b * 4096 + hw0)) * 128;
    for (int ks = 0; ks < 4; ks++) {
      bf16x8 bfrag[4];
      #pragma unroll
      for (int n = 0; n < 4; n++) {
        int p = n0 + n * 16 + colb;
        bfrag[n] = *(const bf16x8*)&inb[(size_t)p * 128 + ks * 32 + cib];
      }
      const unsigned short* wk = wf + ks * 4 * 512;
      #pragma unroll
      for (int m = 0; m < 4; m++) {
        bf16x8 af = *(const bf16x8*)&wk[(m * 64 + l) * 8];
        #pragma unroll
        for (int n = 0; n < 4; n++)
          acc[m][n] = __builtin_amdgcn_mfma_f32_16x16x32_bf16(af, bfrag[n],
                                                              acc[m][n], 0, 0, 0);
      }
    }
    #pragma unroll
    for (int m = 0; m < 4; m++) {
      int d0 = m * 16 + (l >> 4) * 4;
      f32x4 bj = *(const f32x4*)&bias[d0];
      #pragma unroll
      for (int n = 0; n < 4; n++) {
        int p = n0 + n * 16 + colb;
        ushort4v pk = {f2bf(acc[m][n][0] + bj[0]), f2bf(acc[m][n][1] + bj[1]),
                       f2bf(acc[m][n][2] + bj[2]), f2bf(acc[m][n][3] + bj[3])};
        *(ushort4v*)&zt[p * 72 + d0] = pk;
      }
    }
  }
  __syncthreads();
  // ---- phase 2: argmin over 512 codes via MFMA (z from LDS) ----
  {
    bf16x8 zfrag[4][2];
    #pragma unroll
    for (int n = 0; n < 4; n++) {
      int p = n0 + n * 16 + colb;
      #pragma unroll
      for (int k2 = 0; k2 < 2; k2++)
        zfrag[n][k2] = *(const bf16x8*)&zt[p * 72 + k2 * 32 + cib];
    }
    float best[4];
    int bid[4];
    #pragma unroll
    for (int n = 0; n < 4; n++) { best[n] = -1e30f; bid[n] = 0; }
    for (int m = 0; m < 32; m++) {
      bf16x8 a0 = *(const bf16x8*)&cbf[((size_t)(m * 2 + 0) * 64 + l) * 8];
      bf16x8 a1 = *(const bf16x8*)&cbf[((size_t)(m * 2 + 1) * 64 + l) * 8];
      int code0 = m * 16 + (l >> 4) * 4;
      f32x4 ch = *(const f32x4*)&cbh[code0];
      #pragma unroll
      for (int n = 0; n < 4; n++) {
        f32x4 acc2 = (f32x4){0.f, 0.f, 0.f, 0.f};
        acc2 = __builtin_amdgcn_mfma_f32_16x16x32_bf16(a0, zfrag[n][0], acc2, 0, 0, 0);
        acc2 = __builtin_amdgcn_mfma_f32_16x16x32_bf16(a1, zfrag[n][1], acc2, 0, 0, 0);
        #pragma unroll
        for (int r = 0; r < 4; r++) {
          float sc = acc2[r] - ch[r];
          if (sc > best[n]) { best[n] = sc; bid[n] = code0 + r; }
        }
      }
    }
    #pragma unroll
    for (int n = 0; n < 4; n++) {
      #pragma unroll
      for (int off = 16; off <= 32; off <<= 1) {
        float ob = __shfl_xor(best[n], off, 64);
        int oi = __shfl_xor(bid[n], off, 64);
        if (ob > best[n] || (ob == best[n] && oi < bid[n])) {
          best[n] = ob;
          bid[n] = oi;
        }
      }
      if ((l >> 4) == 0) bidx_s[n0 + n * 16 + colb] = (unsigned short)bid[n];
    }
  }
  __syncthreads();
  int bi = bidx_s[t];
  bidx[(size_t)b * 4096 + hw0 + t] = (unsigned short)bi;
  // ---- phase 3: apply (q = cb[idx]) + loss partial (z from LDS) ----
  {
    const float* cq = cb + bi * 64;
    unsigned short* qp = q + ((size_t)(b * 4096 + hw0 + t)) * 64;
    const unsigned short* zp = &zt[t * 72];
    float ls = 0.f;
    #pragma unroll
    for (int g = 0; g < 8; g++) {
      u32x4 zv = *(const u32x4*)&zp[g * 8];
      u32x4 qv;
      #pragma unroll
      for (int h = 0; h < 4; h++) {
        int d = g * 8 + h * 2;
        float q0 = cq[d], q1 = cq[d + 1];
        float z0 = __uint_as_float(zv[h] << 16);
        float z1 = __uint_as_float(zv[h] & 0xFFFF0000u);
        float d0 = q0 - z0, d1 = q1 - z1;
        ls = fmaf(d0, d0, ls);
        ls = fmaf(d1, d1, ls);
        qv[h] = (unsigned)f2bf(q0) | ((unsigned)f2bf(q1) << 16);
      }
      *(u32x4*)&qp[g * 8] = qv;
    }
    red[t] = ls;
    __syncthreads();
    for (int s = 128; s > 0; s >>= 1) {
      if (t < s) red[t] += red[t + s];
      __syncthreads();
    }
    if (t == 0) part[part_off + blk] = red[0];
  }
}

// ---------- histogram from index array ----------
__global__ __launch_bounds__(1024) void vq_hist_k(
    const unsigned short* __restrict__ bidx, int* __restrict__ hist) {
  __shared__ int hl[512];
  int t = threadIdx.x;
  if (t < 512) hl[t] = 0;
  __syncthreads();
  int base = blockIdx.x * 16384;
  for (int i = t; i < 16384; i += 1024)
    atomicAdd(&hl[bidx[base + i]], 1);
  __syncthreads();
  if (t < 512 && hl[t] > 0) atomicAdd(&hist[t], hl[t]);
}

// ---------- t1 via MFMA, async-staged NHWC: convT 4x4 s2 p1, 128->64 --------
// R16: reverted to (256,2) — the verified 596.8us R13 configuration. Both
// occupancy probes failed with the now-understood mechanism: gfx950's
// UNIFIED VGPR+AGPR budget means (256,4) caps total at 128 (R14: spill,
// 9x slower) and (256,3) at ~168 split arch/acc (R15: still spills).
// acc[4][8] + staging state needs the full 256-reg budget -> 2 blocks/CU
// is this kernel's hard occupancy cap.
__global__ __launch_bounds__(256, 2) void t1m_k(
    const unsigned short* __restrict__ in,  // bf16 NHWC (b,64,64,128)
    const unsigned short* __restrict__ wf, const float* __restrict__ bias,
    unsigned short* __restrict__ out) {     // bf16 NHWC (b,128,128,64)
  __shared__ unsigned short patch[1088 * 8];
  int blk = xcd_swz(blockIdx.x, gridDim.x);
  int b = blk >> 5;
  int a0 = (blk & 31) * 2;
  int t = threadIdx.x;
  int w = t >> 6, l = t & 63;
  int sy = w >> 1, sx = w & 1;
  int qr = l >> 4, colb = l & 15;
  f32x4 acc[4][8];
  #pragma unroll
  for (int m = 0; m < 4; m++)
    #pragma unroll
    for (int n = 0; n < 8; n++) acc[m][n] = (f32x4){0.f, 0.f, 0.f, 0.f};
  const unsigned short* inb = in + (size_t)b * 4096 * 128;
  for (int ks = 0; ks < 4; ks++) {
    __syncthreads();
    for (int j = 0; j < 5; j++) {
      int base_chunk = j * 256 + w * 64;   // wave-uniform
      if (base_chunk >= 1088) break;
      int chunk = base_chunk + l;
      int pos = chunk >> 2, qs = chunk & 3;
      int r = pos / 66, c = pos - r * 66;
      int y = a0 - 1 + r, x = c - 1;
      int qg = qs ^ ((pos >> 1) & 3);
      if (pos < 264 && (unsigned)y < 64u && (unsigned)x < 64u) {
        __builtin_amdgcn_global_load_lds(
            (const __attribute__((address_space(1))) unsigned int*)(const void*)
                &inb[((size_t)(y * 64 + x)) * 128 + ks * 32 + qg * 8],
            (__attribute__((address_space(3))) unsigned int*)(void*)
                &patch[(size_t)base_chunk * 8],
            16, 0, 0);
      } else {
        *(bf16x8*)&patch[chunk * 8] = (bf16x8){0, 0, 0, 0, 0, 0, 0, 0};
      }
    }
    __syncthreads();
    __builtin_amdgcn_s_setprio(1);
    const unsigned short* wpar = wf + (size_t)((sy * 2 + sx) * 4 + ks) * 8192;
    #pragma unroll
    for (int tap = 0; tap < 4; tap++) {
      int ty = tap >> 1, tx = tap & 1;
      int d = sy ? ty + 1 : ty;
      int e = sx ? tx + 1 : tx;
      bf16x8 bfrag[8];
      #pragma unroll
      for (int n = 0; n < 8; n++) {
        int p = n * 16 + colb;
        int ar = p >> 6, pc = p & 63;
        int pos = (ar + d) * 66 + (pc + e);
        int qsl = qr ^ ((pos >> 1) & 3);
        bfrag[n] = *(const bf16x8*)&patch[pos * 32 + qsl * 8];
      }
      bf16x8 afrag[4];
      #pragma unroll
      for (int m = 0; m < 4; m++)
        afrag[m] = *(const bf16x8*)&wpar[(tap * 256 + m * 64 + l) * 8];
      #pragma unroll
      for (int m = 0; m < 4; m++)
        #pragma unroll
        for (int n = 0; n < 8; n++)
          acc[m][n] = __builtin_amdgcn_mfma_f32_16x16x32_bf16(
              afrag[m], bfrag[n], acc[m][n], 0, 0, 0);
    }
    __builtin_amdgcn_s_setprio(0);
  }
  #pragma unroll
  for (int m = 0; m < 4; m++) {
    int cob = m * 16 + (l >> 4) * 4;
    float b0 = bias[cob], b1 = bias[cob + 1], b2 = bias[cob + 2],
          b3 = bias[cob + 3];
    #pragma unroll
    for (int n = 0; n < 8; n++) {
      int p = n * 16 + colb;
      int ar = p >> 6, pc = p & 63;
      int oy = 2 * (a0 + ar) + sy, ox = 2 * pc + sx;
      ushort4v pk;
      pk.x = f2bf(fmaxf(acc[m][n][0] + b0, 0.f));
      pk.y = f2bf(fmaxf(acc[m][n][1] + b1, 0.f));
      pk.z = f2bf(fmaxf(acc[m][n][2] + b2, 0.f));
      pk.w = f2bf(fmaxf(acc[m][n][3] + b3, 0.f));
      *(ushort4v*)&out[((size_t)b * 16384 + oy * 128 + ox) * 64 + cob] = pk;
    }
  }
}

// ---------- t2 via MFMA, async-staged NHWC: convT 4x4 s2 p1, 64->3 ----------
// R16: reverted to (256,2) — the verified 596.8us R13 configuration.
__global__ __launch_bounds__(256, 2) void t2m_k(
    const unsigned short* __restrict__ in,  // bf16 NHWC (b,128,128,64)
    const unsigned short* __restrict__ wf,
    const float* __restrict__ bias, float* __restrict__ out) {
  __shared__ unsigned short patch[2112 * 8];
  int blk = xcd_swz(blockIdx.x, gridDim.x);
  int b = blk >> 6;
  int a0 = (blk & 63) * 2;
  int t = threadIdx.x;
  int w = t >> 6, l = t & 63;
  int sy = w >> 1, sx = w & 1;
  int qr = l >> 4, colb = l & 15;
  f32x4 acc[2][8];
  #pragma unroll
  for (int ar = 0; ar < 2; ar++)
    #pragma unroll
    for (int n = 0; n < 8; n++) acc[ar][n] = (f32x4){0.f, 0.f, 0.f, 0.f};
  bf16x8 af[2][4];
  #pragma unroll
  for (int ks = 0; ks < 2; ks++) {
    const unsigned short* wpar = wf + (size_t)((sy * 2 + sx) * 2 + ks) * 2048;
    #pragma unroll
    for (int tap = 0; tap < 4; tap++)
      af[ks][tap] = *(const bf16x8*)&wpar[(tap * 64 + l) * 8];
  }
  const unsigned short* inb = in + (size_t)b * 16384 * 64;
  for (int ks = 0; ks < 2; ks++) {
    __syncthreads();
    for (int j = 0; j < 9; j++) {
      int base_chunk = j * 256 + w * 64;   // wave-uniform
      if (base_chunk >= 2112) break;
      int chunk = base_chunk + l;
      int pos = chunk >> 2, qs = chunk & 3;
      int r = pos / 132, c = pos - r * 132;
      int y = a0 - 1 + r, x = c - 1;
      int qg = qs ^ ((pos >> 1) & 3);
      if ((unsigned)y < 128u && (unsigned)x < 128u) {
        __builtin_amdgcn_global_load_lds(
            (const __attribute__((address_space(1))) unsigned int*)(const void*)
                &inb[((size_t)(y * 128 + x)) * 64 + ks * 32 + qg * 8],
            (__attribute__((address_space(3))) unsigned int*)(void*)
                &patch[(size_t)base_chunk * 8],
            16, 0, 0);
      } else {
        *(bf16x8*)&patch[chunk * 8] = (bf16x8){0, 0, 0, 0, 0, 0, 0, 0};
      }
    }
    __syncthreads();
    __builtin_amdgcn_s_setprio(1);
    #pragma unroll
    for (int tap = 0; tap < 4; tap++) {
      int ty = tap >> 1, tx = tap & 1;
      int d = sy ? ty + 1 : ty;
      int e = sx ? tx + 1 : tx;
      #pragma unroll
      for (int ar = 0; ar < 2; ar++) {
        #pragma unroll
        for (int n = 0; n < 8; n++) {
          int pc = n * 16 + colb;
          int pos = (ar + d) * 132 + (pc + e);
          int qsl = qr ^ ((pos >> 1) & 3);
          bf16x8 bfrag = *(const bf16x8*)&patch[pos * 32 + qsl * 8];
          acc[ar][n] = __builtin_amdgcn_mfma_f32_16x16x32_bf16(
              af[ks][tap], bfrag, acc[ar][n], 0, 0, 0);
        }
      }
    }
    __builtin_amdgcn_s_setprio(0);
  }
  int rb = (l >> 4) * 4;
  #pragma unroll
  for (int r = 0; r < 4; r++) {
    int co = rb + r;
    if (co < 3) {
      float bj = bias[co];
      #pragma unroll
      for (int ar = 0; ar < 2; ar++) {
        int oy = 2 * (a0 + ar) + sy;
        #pragma unroll
        for (int n = 0; n < 8; n++) {
          int pc = n * 16 + colb;
          int ox = 2 * pc + sx;
          out[((size_t)(b * 3 + co)) * 65536 + oy * 256 + ox] = acc[ar][n][r] + bj;
        }
      }
    }
  }
}

// ---------- finalize: loss + perplexity ----------
__global__ __launch_bounds__(512) void fin_k(
    const float* __restrict__ part, const int* __restrict__ hist,
    float* __restrict__ loss_out, float* __restrict__ perp_out) {
  __shared__ float red[512];
  int t = threadIdx.x;
  red[t] = part[t];
  __syncthreads();
  for (int s = 256; s > 0; s >>= 1) {
    if (t < s) red[t] += red[t + s];
    __syncthreads();
  }
  float loss = 1.25f * red[0] / 8388608.f;
  __syncthreads();
  float p = (float)hist[t] / 131072.f;
  red[t] = -p * logf(p + 1e-10f);
  __syncthreads();
  for (int s = 256; s > 0; s >>= 1) {
    if (t < s) red[t] += red[t + s];
    __syncthreads();
  }
  if (t == 0) {
    *loss_out = loss;
    *perp_out = expf(red[0]);
  }
}

// ---------------------------------------------------------------------------
extern "C" void kernel_launch(void* const* d_in, const int* in_sizes, int n_in,
                              void* d_out, int out_size, void* d_ws, size_t ws_size,
                              hipStream_t stream) {
  (void)in_sizes; (void)n_in; (void)out_size;
  const float* x    = (const float*)d_in[0];
  const float* e1w  = (const float*)d_in[1];
  const float* e1b  = (const float*)d_in[2];
  const float* e2w  = (const float*)d_in[3];
  const float* e2b  = (const float*)d_in[4];
  const float* er11 = (const float*)d_in[5];
  const float* er12 = (const float*)d_in[6];
  const float* er21 = (const float*)d_in[7];
  const float* er22 = (const float*)d_in[8];
  const float* pvw  = (const float*)d_in[9];
  const float* pvb  = (const float*)d_in[10];
  const float* cb   = (const float*)d_in[11];
  const float* d1w  = (const float*)d_in[12];
  const float* d1b  = (const float*)d_in[13];
  const float* dr11 = (const float*)d_in[14];
  const float* dr12 = (const float*)d_in[15];
  const float* dr21 = (const float*)d_in[16];
  const float* dr22 = (const float*)d_in[17];
  const float* t1w  = (const float*)d_in[18];
  const float* t1b  = (const float*)d_in[19];
  const float* t2w  = (const float*)d_in[20];
  const float* t2b  = (const float*)d_in[21];
  float* out = (float*)d_out;

  // ---- workspace layout (float offsets) ----
  const size_t W_PVF  = 0;
  const size_t W_E2F  = W_PVF + 4096;
  const size_t W_T1F  = W_E2F + 65536;
  const size_t W_T2F  = W_T1F + 65536;
  const size_t W_D1F  = W_T2F + 8192;
  const size_t W_CBF  = W_D1F + 36864;
  const size_t W_E1F  = W_CBF + 16384;
  const size_t W_RT   = W_E1F + 2048;
  const size_t W_CBH  = W_RT + 8 * 73728;
  const size_t W_PART = W_CBH + 512;
  const size_t W_BIDX = W_PART + 512;
  const size_t W_HIST = W_BIDX + 65536;
  const size_t W_TOT  = W_HIST + 512;

  float* ws = (float*)d_ws;
  unsigned short* pvf = (unsigned short*)(ws + W_PVF);
  unsigned short* e2f = (unsigned short*)(ws + W_E2F);
  unsigned short* t1f = (unsigned short*)(ws + W_T1F);
  unsigned short* t2f = (unsigned short*)(ws + W_T2F);
  unsigned short* d1f = (unsigned short*)(ws + W_D1F);
  unsigned short* cbf = (unsigned short*)(ws + W_CBF);
  unsigned short* e1f = (unsigned short*)(ws + W_E1F);
  unsigned short* rtf[8];
  for (int i = 0; i < 8; i++)
    rtf[i] = (unsigned short*)(ws + W_RT + (size_t)i * 73728);
  float* cbh  = ws + W_CBH;
  float* part = ws + W_PART;
  unsigned short* bidx = (unsigned short*)(ws + W_BIDX);
  int*   hist = (int*)(ws + W_HIST);

  size_t wfloats = ws_size / sizeof(float);
  int BC = 32;
  while (BC > 1 && W_TOT + (size_t)BC * 1572864 > wfloats) BC >>= 1;
  int nchunk = 32 / BC;

  // dynamic buffers (bf16 NHWC): E1/T1 (overlaid), P1, P2, P4, Zbf, Qbf
  unsigned short* E1  = (unsigned short*)(ws + W_TOT);             // BC*1048576 ush
  unsigned short* P1  = (unsigned short*)(ws + W_TOT + (size_t)BC * 524288);
  unsigned short* P2  = P1 + (size_t)BC * 524288;
  unsigned short* P4  = P2 + (size_t)BC * 524288;
  unsigned short* Zbf = P4 + (size_t)BC * 524288;                  // unused slot
  unsigned short* Qbf = Zbf + (size_t)BC * 262144;

  init_k<<<1, 512, 0, stream>>>(hist);
  cbh_k<<<2, 256, 0, stream>>>(cb, cbh);
  repack_cbf_k<<<128, 256, 0, stream>>>(cb, cbf);

  repack_e1f_k<<<16, 256, 0, stream>>>(e1w, e1f);
  repack_pvf_k<<<32, 256, 0, stream>>>(pvw, pvf);
  repack_e2f_k<<<512, 256, 0, stream>>>(e2w, e2f);
  repack_t1f_k<<<512, 256, 0, stream>>>(t1w, t1f);
  repack_t2f_k<<<64, 256, 0, stream>>>(t2w, t2f);
  repack_frag_k<64><<<288, 256, 0, stream>>>(d1w, d1f);
  repack_frag_k<128><<<576, 256, 0, stream>>>(er11, rtf[0]);
  repack_frag_k<128><<<576, 256, 0, stream>>>(er12, rtf[1]);
  repack_frag_k<128><<<576, 256, 0, stream>>>(er21, rtf[2]);
  repack_frag_k<128><<<576, 256, 0, stream>>>(er22, rtf[3]);
  repack_frag_k<128><<<576, 256, 0, stream>>>(dr11, rtf[4]);
  repack_frag_k<128><<<576, 256, 0, stream>>>(dr12, rtf[5]);
  repack_frag_k<128><<<576, 256, 0, stream>>>(dr21, rtf[6]);
  repack_frag_k<128><<<576, 256, 0, stream>>>(dr22, rtf[7]);

  for (int c = 0; c < nchunk; ++c) {
    const float* xc = x + (size_t)c * BC * 3 * 65536;
    float* outc = out + 1 + (size_t)c * BC * 3 * 65536;
    unsigned short* bidxc = bidx + (size_t)c * BC * 4096;
    // encoder
    e1m_k<<<BC * 128, 256, 0, stream>>>(xc, e1f, e1b, E1);
    e2m_k<<<BC * 64, 256, 0, stream>>>(E1, e2f, e2b, P1);  // P1 = x0 pre-act
    // res stack 1: consumers ReLU the pre-act on the fly
    conv3nh_k<128, false, true,  false, false><<<BC * 32, 256, 0, stream>>>(P1, rtf[0], nullptr, nullptr, P4);
    conv3nh_k<128, true,  false, false, false><<<BC * 32, 256, 0, stream>>>(P4, rtf[1], nullptr, P1, P2);  // x1
    conv3nh_k<128, false, false, false, false><<<BC * 32, 256, 0, stream>>>(P2, rtf[2], nullptr, nullptr, P4);
    conv3nh_k<128, true,  false, false, false><<<BC * 32, 256, 0, stream>>>(P4, rtf[3], nullptr, P2, P1);  // x2
    // fused vector quantization: pvq conv + argmin + apply + loss partials
    vqf_k<<<BC * 16, 256, 0, stream>>>(P1, pvf, pvb, cbf, cbh, cb, Qbf, bidxc,
                                       part, c * BC * 16);
    // decoder: d1 writes pre-act only; consumer ReLUs while staging
    conv3nh_k<64,  false, false, true,  true ><<<BC * 32, 256, 0, stream>>>(Qbf, d1f, d1b, nullptr, P1);   // P1 = h pre
    conv3nh_k<128, false, true,  false, false><<<BC * 32, 256, 0, stream>>>(P1, rtf[4], nullptr, nullptr, P4);
    conv3nh_k<128, true,  false, false, false><<<BC * 32, 256, 0, stream>>>(P4, rtf[5], nullptr, P1, P2);  // h1
    conv3nh_k<128, false, false, false, false><<<BC * 32, 256, 0, stream>>>(P2, rtf[6], nullptr, nullptr, P4);
    conv3nh_k<128, true,  false, false, false><<<BC * 32, 256, 0, stream>>>(P4, rtf[7], nullptr, P2, P1);  // hres
    t1m_k<<<BC * 32, 256, 0, stream>>>(P1, t1f, t1b, E1);  // T1out overlays E1
    t2m_k<<<BC * 64, 256, 0, stream>>>(E1, t2f, t2b, outc);
  }
  vq_hist_k<<<8, 1024, 0, stream>>>(bidx, hist);
  fin_k<<<1, 512, 0, stream>>>(part, hist, out, out + 1 + 6291456);
}